// Round 7
// baseline (1462.861 us; speedup 1.0000x reference)
//
#include <hip/hip_runtime.h>
#include <hip/hip_bf16.h>
#include <cstdint>

#define NROWS 262144
#define HDIM  512
#define NENT  100000
#define SCAN_NBLK ((NENT + 1023) / 1024)

typedef __attribute__((ext_vector_type(4))) float  f32x4;
typedef __attribute__((ext_vector_type(8))) short  bf16x8;

static __device__ __forceinline__ unsigned short f2bf(float x) {
    unsigned u = __float_as_uint(x);
    u += 0x7FFF + ((u >> 16) & 1);          // round-to-nearest-even
    return (unsigned short)(u >> 16);
}
static __device__ __forceinline__ float bf2f(unsigned short h) {
    unsigned u = ((unsigned)h) << 16;
    return __uint_as_float(u);
}

// Pack W ([512][1024] row-major, y = x @ W.T) into per-wave-linear MFMA
// A-fragment order: Wp[w][kt][ct][lane] (bf16x8 each), nt = w*4+ct.
// Lane l of fragment (nt,kt) holds A[m = nt*16+(l&15)][k = kt*32+(l>>4)*8+j].
// Wave w in fuse_kernel then streams its 64 KB of W CONTIGUOUSLY.
__global__ void pack_w_kernel(const float* __restrict__ W, unsigned short* __restrict__ Wp) {
    int g    = blockIdx.x * 256 + threadIdx.x;   // 65536 slots
    int lane = g & 63;
    int ct   = (g >> 6) & 3;
    int kt   = (g >> 8) & 31;
    int w    = g >> 13;
    int nt   = w * 4 + ct;
    int col  = nt * 16 + (lane & 15);
    int k    = kt * 32 + ((lane >> 4) << 3);
    const float* src = W + (size_t)col * 1024 + k;
    f32x4 v0 = *(const f32x4*)(src);
    f32x4 v1 = *(const f32x4*)(src + 4);
    bf16x8 ov;
#pragma unroll
    for (int i = 0; i < 4; ++i) {
        ov[i]     = (short)f2bf(v0[i]);
        ov[4 + i] = (short)f2bf(v1[i]);
    }
    *(bf16x8*)(Wp + (size_t)g * 8) = ov;
}

// ---- CSR build: counts -> 2-level exclusive scan -> fill row indices ----
__global__ __launch_bounds__(256) void count_kernel(const int* __restrict__ ids,
                                                    unsigned* __restrict__ counts) {
    int r = blockIdx.x * 256 + threadIdx.x;
    if (r < NROWS) atomicAdd(&counts[ids[r]], 1u);
}

__global__ __launch_bounds__(1024) void scan1_kernel(const unsigned* __restrict__ counts,
                                                     unsigned* __restrict__ off,
                                                     unsigned* __restrict__ bsums) {
    __shared__ unsigned tmp[1024];
    int i = blockIdx.x * 1024 + threadIdx.x;
    unsigned v = (i < NENT) ? counts[i] : 0u;
    tmp[threadIdx.x] = v;
    __syncthreads();
#pragma unroll
    for (int o = 1; o < 1024; o <<= 1) {
        unsigned a = (threadIdx.x >= o) ? tmp[threadIdx.x - o] : 0u;
        __syncthreads();
        tmp[threadIdx.x] += a;
        __syncthreads();
    }
    if (i < NENT) off[i] = tmp[threadIdx.x] - v;     // block-local exclusive
    if (threadIdx.x == 1023) bsums[blockIdx.x] = tmp[1023];
}

__global__ void scan2_kernel(unsigned* __restrict__ bsums) {
    if (threadIdx.x == 0 && blockIdx.x == 0) {
        unsigned s = 0;
        for (int i = 0; i < SCAN_NBLK; ++i) { unsigned t = bsums[i]; bsums[i] = s; s += t; }
    }
}

__global__ __launch_bounds__(1024) void scan3_kernel(unsigned* __restrict__ off,
                                                     const unsigned* __restrict__ bsums,
                                                     unsigned* __restrict__ cursor) {
    int i = blockIdx.x * 1024 + threadIdx.x;
    if (i < NENT) {
        unsigned o = off[i] + bsums[blockIdx.x];
        off[i] = o;
        cursor[i] = o;
    }
    if (i == 0) off[NENT] = NROWS;
}

__global__ __launch_bounds__(256) void fill_kernel(const int* __restrict__ ids,
                                                   unsigned* __restrict__ cursor,
                                                   int* __restrict__ rowidx) {
    int r = blockIdx.x * 256 + threadIdx.x;
    if (r < NROWS) {
        unsigned p = atomicAdd(&cursor[ids[r]], 1u);
        rowidx[p] = r;
    }
}

// Fused gate path v4: 32 rows/block x 512 cols; whole K = [emb | LN(state)]
// staged once as bf16 fragments in LDS (64 KB), then a barrier-free K-loop
// with a DEPTH-4 register pipeline on both W (L2, per-wave-linear Wp) and
// x (LDS). All stage arrays statically indexed (full unroll).
__global__ __launch_bounds__(512, 3) void fuse_kernel(
    const float* __restrict__ emb, const float* __restrict__ slow,
    const unsigned short* __restrict__ Wp, const float* __restrict__ bias,
    const int* __restrict__ ids, float* __restrict__ out)
{
    __shared__ unsigned short xLds[64 * 64 * 8];   // 64 KB
    __shared__ float muS[32], rsS[32], actS[32], bS[512];
    __shared__ int idS[32];

    const int t    = threadIdx.x;
    const int w    = t >> 6;          // 0..7
    const int lane = t & 63;
    const int brow = blockIdx.x * 32;

    if (t < 128) ((f32x4*)bS)[t] = ((const f32x4*)bias)[t];

    // ---- LN stats + is_active: 8 waves x 4 rows ----
    for (int rr = 0; rr < 4; ++rr) {
        int row = w * 4 + rr;
        int id  = ids[brow + row];
        const float* sp = slow + (size_t)id * HDIM;
        f32x4 v0 = ((const f32x4*)sp)[lane * 2];
        f32x4 v1 = ((const f32x4*)sp)[lane * 2 + 1];
        float s = 0.f, s2 = 0.f, sa = 0.f;
#pragma unroll
        for (int i = 0; i < 4; ++i) {
            s  += v0[i] + v1[i];
            s2 += v0[i] * v0[i] + v1[i] * v1[i];
            sa += fabsf(v0[i]) + fabsf(v1[i]);
        }
#pragma unroll
        for (int m = 32; m >= 1; m >>= 1) {
            s  += __shfl_xor(s, m);
            s2 += __shfl_xor(s2, m);
            sa += __shfl_xor(sa, m);
        }
        if (lane == 0) {
            float mu  = s * (1.f / HDIM);
            float var = s2 * (1.f / HDIM) - mu * mu;
            muS[row]  = mu;
            rsS[row]  = rsqrtf(var + 1e-5f);
            actS[row] = (sa > 1e-6f) ? 1.f : 0.f;
            idS[row]  = id;
        }
    }
    __syncthreads();

    // ---- stage whole K as bf16 fragments: 4096 lane-slots / 512 threads ----
    for (int slot = t; slot < 4096; slot += 512) {
        int T    = slot >> 6;
        int ls   = slot & 63;
        int kt   = T >> 1;
        int row  = (T & 1) * 16 + (ls & 15);
        int k    = kt * 32 + ((ls >> 4) << 3);
        f32x4 x0, x1;
        if (k < 512) {
            const float* p = emb + (size_t)(brow + row) * HDIM + k;
            x0 = *(const f32x4*)p;
            x1 = *(const f32x4*)(p + 4);
        } else {
            const float* p = slow + (size_t)idS[row] * HDIM + (k - 512);
            x0 = *(const f32x4*)p;
            x1 = *(const f32x4*)(p + 4);
            float mu = muS[row], rs = rsS[row];
#pragma unroll
            for (int i = 0; i < 4; ++i) {
                x0[i] = (x0[i] - mu) * rs;
                x1[i] = (x1[i] - mu) * rs;
            }
        }
        bf16x8 av;
#pragma unroll
        for (int i = 0; i < 4; ++i) {
            av[i]     = (short)f2bf(x0[i]);
            av[4 + i] = (short)f2bf(x1[i]);
        }
        ((bf16x8*)xLds)[slot] = av;
    }
    __syncthreads();

    // ---- barrier-free K loop, depth-4 pipeline ----
    f32x4 zero4 = {0.f, 0.f, 0.f, 0.f};
    f32x4 acc[2][4];                    // [rt][ct]
#pragma unroll
    for (int i = 0; i < 2; ++i)
#pragma unroll
        for (int j = 0; j < 4; ++j) acc[i][j] = zero4;

    // per-wave-linear W stream: base + (kt*4+ct)*512 elements
    const unsigned short* wpW = Wp + (size_t)w * 65536 + (size_t)lane * 8;
    const bf16x8* xBase = (const bf16x8*)xLds + lane;

#define LOADW(dst, kt)                                                  \
    {   _Pragma("unroll")                                               \
        for (int ct = 0; ct < 4; ++ct)                                  \
            dst[ct] = *(const bf16x8*)(wpW + ((kt) * 4 + ct) * 512);    \
    }
#define LOADX(dst, kt)                                                  \
    {   _Pragma("unroll")                                               \
        for (int rt = 0; rt < 2; ++rt)                                  \
            dst[rt] = xBase[((kt) * 2 + rt) * 64];                      \
    }
#define STEP(wf, xf)                                                    \
    {   _Pragma("unroll")                                               \
        for (int ct = 0; ct < 4; ++ct) {                                \
            acc[0][ct] = __builtin_amdgcn_mfma_f32_16x16x32_bf16(wf[ct], xf[0], acc[0][ct], 0, 0, 0); \
            acc[1][ct] = __builtin_amdgcn_mfma_f32_16x16x32_bf16(wf[ct], xf[1], acc[1][ct], 0, 0, 0); \
        }                                                               \
    }

    bf16x8 wQ0[4], wQ1[4], wQ2[4], wQ3[4];
    bf16x8 xQ0[2], xQ1[2], xQ2[2], xQ3[2];

    LOADW(wQ0, 0); LOADX(xQ0, 0);
    LOADW(wQ1, 1); LOADX(xQ1, 1);
    LOADW(wQ2, 2); LOADX(xQ2, 2);
#pragma unroll
    for (int kt = 0; kt < 32; kt += 4) {
        if (kt + 3 < 32) { LOADW(wQ3, kt + 3); LOADX(xQ3, kt + 3); }
        STEP(wQ0, xQ0);
        if (kt + 4 < 32) { LOADW(wQ0, kt + 4); LOADX(xQ0, kt + 4); }
        STEP(wQ1, xQ1);
        if (kt + 5 < 32) { LOADW(wQ1, kt + 5); LOADX(xQ1, kt + 5); }
        STEP(wQ2, xQ2);
        if (kt + 6 < 32) { LOADW(wQ2, kt + 6); LOADX(xQ2, kt + 6); }
        STEP(wQ3, xQ3);
    }
#undef LOADW
#undef LOADX
#undef STEP

    // ---- epilogue: bias+sigmoid+fuse; emb/h from LDS (bf16); f32x4 store ----
#pragma unroll
    for (int rt = 0; rt < 2; ++rt) {
        int rowl = rt * 16 + (lane & 15);
        int grow = brow + rowl;
        float act = actS[rowl];
        float* outP = out + (size_t)grow * HDIM;
#pragma unroll
        for (int ct = 0; ct < 4; ++ct) {
            int col0 = w * 64 + ct * 16 + ((lane >> 4) << 2);
            // emb[row][col0..3] from LDS: k = col0
            int Te = ((col0 >> 5) * 2 + rt) * 64 + (((col0 >> 3) & 3) << 4) + (lane & 15);
            const unsigned short* pe = xLds + Te * 8 + (col0 & 7);
            // h[row][col0..3] from LDS: k = 512 + col0
            int kh = 512 + col0;
            int Th = ((kh >> 5) * 2 + rt) * 64 + (((kh >> 3) & 3) << 4) + (lane & 15);
            const unsigned short* ph = xLds + Th * 8 + (kh & 7);
            f32x4 bv = *(const f32x4*)&bS[col0];
            f32x4 o;
#pragma unroll
            for (int r = 0; r < 4; ++r) {
                float ev = bf2f(pe[r]);
                float hv = bf2f(ph[r]);
                float logit = acc[rt][ct][r] + bv[r];
                float z  = 1.f / (1.f + __expf(-logit));
                float fused = z * ev + (1.f - z) * hv;
                o[r] = (act > 0.f) ? fused : ev;
            }
            *(f32x4*)(outP + col0) = o;
        }
    }
}

// Per-entity: gather its rows from `out` (CSR), mean -> EMA fast, norm-gated slow.
__global__ __launch_bounds__(256) void finalize_kernel(
    const float* __restrict__ fast, const float* __restrict__ slow,
    const float* __restrict__ out, const unsigned* __restrict__ off,
    const int* __restrict__ rowidx, float* __restrict__ nf, float* __restrict__ ns)
{
    int e = blockIdx.x * 4 + (threadIdx.x >> 6);
    if (e >= NENT) return;
    int lane = threadIdx.x & 63;
    size_t base = (size_t)e * HDIM + lane * 8;

    f32x4 f0 = *(const f32x4*)(fast + base), f1 = *(const f32x4*)(fast + base + 4);
    f32x4 l0 = *(const f32x4*)(slow + base), l1 = *(const f32x4*)(slow + base + 4);

    unsigned o0 = off[e], o1 = off[e + 1];
    int c = (int)(o1 - o0);

    if (c == 0) {
        *(f32x4*)(nf + base)     = f0;
        *(f32x4*)(nf + base + 4) = f1;
        *(f32x4*)(ns + base)     = l0;
        *(f32x4*)(ns + base + 4) = l1;
        return;
    }

    f32x4 s0 = {0.f, 0.f, 0.f, 0.f}, s1 = {0.f, 0.f, 0.f, 0.f};
    for (int j = 0; j < c; ++j) {
        int r = rowidx[o0 + j];
        const float* p = out + (size_t)r * HDIM + lane * 8;
        s0 += *(const f32x4*)p;
        s1 += *(const f32x4*)(p + 4);
    }

    float inv = 0.5f / (float)c;          // ALPHA / count
    f32x4 n0, n1, d0, d1;
    float ss = 0.f;
#pragma unroll
    for (int i = 0; i < 4; ++i) {
        n0[i] = 0.5f * f0[i] + s0[i] * inv;
        n1[i] = 0.5f * f1[i] + s1[i] * inv;
        d0[i] = n0[i] - l0[i]; ss += d0[i] * d0[i];
        d1[i] = n1[i] - l1[i]; ss += d1[i] * d1[i];
    }
#pragma unroll
    for (int m = 32; m >= 1; m >>= 1) ss += __shfl_xor(ss, m);
    float delta = sqrtf(ss);
    float gate  = 1.f / (1.f + expf(-5.f * (delta - 0.5f)));

    f32x4 o0v, o1v;
#pragma unroll
    for (int i = 0; i < 4; ++i) {
        o0v[i] = l0[i] + gate * d0[i];
        o1v[i] = l1[i] + gate * d1[i];
    }
    *(f32x4*)(nf + base)     = n0;
    *(f32x4*)(nf + base + 4) = n1;
    *(f32x4*)(ns + base)     = o0v;
    *(f32x4*)(ns + base + 4) = o1v;
}

extern "C" void kernel_launch(void* const* d_in, const int* in_sizes, int n_in,
                              void* d_out, int out_size, void* d_ws, size_t ws_size,
                              hipStream_t stream) {
    const float* emb  = (const float*)d_in[0];
    const float* slow = (const float*)d_in[1];
    const float* fast = (const float*)d_in[2];
    const float* W    = (const float*)d_in[3];
    const float* bias = (const float*)d_in[4];
    const int*   ids  = (const int*)d_in[5];

    float* out = (float*)d_out;
    float* nf  = out + (size_t)NROWS * HDIM;
    float* ns  = nf + (size_t)NENT * HDIM;

    // ws layout: Wp 1 MiB | counts/cursor 400 KB | offsets 400 KB | bsums | rowidx 1 MiB
    unsigned short* Wp   = (unsigned short*)d_ws;
    unsigned* counts     = (unsigned*)((char*)d_ws + (1u << 20));            // reused as cursor
    unsigned* off        = (unsigned*)((char*)d_ws + (1u << 20) + 512 * 1024);
    unsigned* bsums      = (unsigned*)((char*)d_ws + (2u << 20));
    int*      rowidx     = (int*)((char*)d_ws + (2u << 20) + 4096);

    hipMemsetAsync(counts, 0, (size_t)NENT * sizeof(unsigned), stream);

    pack_w_kernel<<<256, 256, 0, stream>>>(W, Wp);
    count_kernel<<<NROWS / 256, 256, 0, stream>>>(ids, counts);
    scan1_kernel<<<SCAN_NBLK, 1024, 0, stream>>>(counts, off, bsums);
    scan2_kernel<<<1, 64, 0, stream>>>(bsums);
    scan3_kernel<<<SCAN_NBLK, 1024, 0, stream>>>(off, bsums, counts);
    fill_kernel<<<NROWS / 256, 256, 0, stream>>>(ids, counts, rowidx);
    fuse_kernel<<<NROWS / 32, 512, 0, stream>>>(emb, slow, Wp, bias, ids, out);
    finalize_kernel<<<(NENT + 3) / 4, 256, 0, stream>>>(fast, slow, out, off, rowidx, nf, ns);
}

// Round 8
// 1031.910 us; speedup vs baseline: 1.4176x; 1.4176x over previous
//
#include <hip/hip_runtime.h>
#include <hip/hip_bf16.h>
#include <cstdint>

#define NROWS 262144
#define HDIM  512
#define NENT  100000
#define SCAN_NBLK ((NENT + 1023) / 1024)

typedef __attribute__((ext_vector_type(4))) float  f32x4;
typedef __attribute__((ext_vector_type(8))) short  bf16x8;
typedef __attribute__((ext_vector_type(4))) short  bf16x4;

static __device__ __forceinline__ unsigned short f2bf(float x) {
    unsigned u = __float_as_uint(x);
    u += 0x7FFF + ((u >> 16) & 1);          // round-to-nearest-even
    return (unsigned short)(u >> 16);
}

// Pack W ([512][1024] row-major, y = x @ W.T) into PHASE-MAJOR MFMA A-frag
// order: Wp[kt][nt][lane] (bf16x8). Lane l of frag (nt,kt) holds
// A[m = nt*16+(l&15)][k = kt*32+(l>>4)*8+j]. One kt-slice = 32 KB contiguous.
__global__ void pack_w_kernel(const float* __restrict__ W, unsigned short* __restrict__ Wp) {
    int g    = blockIdx.x * 256 + threadIdx.x;   // 65536 slots
    int lane = g & 63;
    int nt   = (g >> 6) & 31;
    int kt   = g >> 11;
    int col  = nt * 16 + (lane & 15);
    int k    = kt * 32 + ((lane >> 4) << 3);
    const float* src = W + (size_t)col * 1024 + k;
    f32x4 v0 = *(const f32x4*)(src);
    f32x4 v1 = *(const f32x4*)(src + 4);
    bf16x8 ov;
#pragma unroll
    for (int i = 0; i < 4; ++i) {
        ov[i]     = (short)f2bf(v0[i]);
        ov[4 + i] = (short)f2bf(v1[i]);
    }
    *(bf16x8*)(Wp + (size_t)g * 8) = ov;
}

// ---- CSR build: counts -> 2-level exclusive scan -> fill row indices ----
__global__ __launch_bounds__(256) void count_kernel(const int* __restrict__ ids,
                                                    unsigned* __restrict__ counts) {
    int r = blockIdx.x * 256 + threadIdx.x;
    if (r < NROWS) atomicAdd(&counts[ids[r]], 1u);
}

__global__ __launch_bounds__(1024) void scan1_kernel(const unsigned* __restrict__ counts,
                                                     unsigned* __restrict__ off,
                                                     unsigned* __restrict__ bsums) {
    __shared__ unsigned tmp[1024];
    int i = blockIdx.x * 1024 + threadIdx.x;
    unsigned v = (i < NENT) ? counts[i] : 0u;
    tmp[threadIdx.x] = v;
    __syncthreads();
#pragma unroll
    for (int o = 1; o < 1024; o <<= 1) {
        unsigned a = (threadIdx.x >= o) ? tmp[threadIdx.x - o] : 0u;
        __syncthreads();
        tmp[threadIdx.x] += a;
        __syncthreads();
    }
    if (i < NENT) off[i] = tmp[threadIdx.x] - v;     // block-local exclusive
    if (threadIdx.x == 1023) bsums[blockIdx.x] = tmp[1023];
}

__global__ void scan2_kernel(unsigned* __restrict__ bsums) {
    if (threadIdx.x == 0 && blockIdx.x == 0) {
        unsigned s = 0;
        for (int i = 0; i < SCAN_NBLK; ++i) { unsigned t = bsums[i]; bsums[i] = s; s += t; }
    }
}

__global__ __launch_bounds__(1024) void scan3_kernel(unsigned* __restrict__ off,
                                                     const unsigned* __restrict__ bsums,
                                                     unsigned* __restrict__ cursor) {
    int i = blockIdx.x * 1024 + threadIdx.x;
    if (i < NENT) {
        unsigned o = off[i] + bsums[blockIdx.x];
        off[i] = o;
        cursor[i] = o;
    }
    if (i == 0) off[NENT] = NROWS;
}

__global__ __launch_bounds__(256) void fill_kernel(const int* __restrict__ ids,
                                                   unsigned* __restrict__ cursor,
                                                   int* __restrict__ rowidx) {
    int r = blockIdx.x * 256 + threadIdx.x;
    if (r < NROWS) {
        unsigned p = atomicAdd(&cursor[ids[r]], 1u);
        rowidx[p] = r;
    }
}

// Fused gate path v5: classic double-LDS GEMM tile. BM=128 rows x BN=512
// cols, BK=32, 1024 threads = 16 waves (2M x 8N, wave = 64r x 64c, acc 4x4).
// BOTH operands staged in LDS (W dbuf 64 KB + x dbuf 16 KB) -> W L1 traffic
// = (M/128) x 1 MiB = 2.1 GB (was 8.6), MFMA fed from LDS with reuse.
// K-order: phases 0..15 = LN(state) (W kt 16..31), 16..31 = emb (W kt 0..15)
// so epilogue emb re-read is L3-hot. One barrier per phase; global->reg
// issued at phase start, ds_write after MFMA (T14 split).
__global__ __launch_bounds__(1024, 4) void fuse_kernel(
    const float* __restrict__ emb, const float* __restrict__ slow,
    const unsigned short* __restrict__ Wp, const float* __restrict__ bias,
    const int* __restrict__ ids, float* __restrict__ out)
{
    __shared__ unsigned short wLds[2][2048 * 8];   // 2 x 32 KB (32 frags x 64 lanes)
    __shared__ unsigned short xLds[2][512 * 8];    // 2 x 8 KB  (8 frags x 64 lanes)
    __shared__ float muS[128], rsS[128], actS[128], bS[512];
    __shared__ int idS[128];

    const int t    = threadIdx.x;
    const int w    = t >> 6;          // 0..15
    const int lane = t & 63;
    const int wm   = w >> 3;          // 0..1  (row half)
    const int wn   = w & 7;           // 0..7  (col group)
    const int brow = blockIdx.x * 128;

    if (t < 128) ((f32x4*)bS)[t] = ((const f32x4*)bias)[t];

    // ---- LN stats + is_active: 16 waves x 8 rows ----
    for (int rr = 0; rr < 8; ++rr) {
        int row = w * 8 + rr;
        int id  = ids[brow + row];
        const float* sp = slow + (size_t)id * HDIM;
        f32x4 v0 = ((const f32x4*)sp)[lane * 2];
        f32x4 v1 = ((const f32x4*)sp)[lane * 2 + 1];
        float s = 0.f, s2 = 0.f, sa = 0.f;
#pragma unroll
        for (int i = 0; i < 4; ++i) {
            s  += v0[i] + v1[i];
            s2 += v0[i] * v0[i] + v1[i] * v1[i];
            sa += fabsf(v0[i]) + fabsf(v1[i]);
        }
#pragma unroll
        for (int m = 32; m >= 1; m >>= 1) {
            s  += __shfl_xor(s, m);
            s2 += __shfl_xor(s2, m);
            sa += __shfl_xor(sa, m);
        }
        if (lane == 0) {
            float mu  = s * (1.f / HDIM);
            float var = s2 * (1.f / HDIM) - mu * mu;
            muS[row]  = mu;
            rsS[row]  = rsqrtf(var + 1e-5f);
            actS[row] = (sa > 1e-6f) ? 1.f : 0.f;
            idS[row]  = id;
        }
    }
    __syncthreads();

    // ---- per-thread staging geometry ----
    // x: thread covers row = t>>3 (0..127), kloc = (t&7)*4 (4 consecutive k)
    const int xrow = t >> 3;
    const int kloc = (t & 7) * 4;
    const float* srcState = slow + (size_t)idS[xrow] * HDIM + kloc;
    const float* srcEmb   = emb + (size_t)(brow + xrow) * HDIM + kloc;
    const float muR = muS[xrow], rsR = rsS[xrow];
    // x LDS byte offset: frag rt = xrow>>4, lane = ((kloc>>3)<<4)|(xrow&15), j0 = kloc&7
    const int xByte = (((xrow >> 4) * 64 + (((kloc >> 3) << 4) | (xrow & 15))) << 4) + ((kloc & 7) << 1);

    f32x4 zero4 = {0.f, 0.f, 0.f, 0.f};
    f32x4 acc[4][4];                  // [rt][ct]
#pragma unroll
    for (int i = 0; i < 4; ++i)
#pragma unroll
        for (int j = 0; j < 4; ++j) acc[i][j] = zero4;

#define ISSUE(ph, wr0, wr1, xr)                                          \
    {   int ktW = ((ph) < 16) ? (16 + (ph)) : ((ph) - 16);               \
        const bf16x8* wp = (const bf16x8*)(Wp + (size_t)ktW * 16384);    \
        wr0 = wp[t];                                                     \
        wr1 = wp[t + 1024];                                              \
        const float* xp = ((ph) < 16) ? (srcState + (ph) * 32)           \
                                      : (srcEmb + ((ph) - 16) * 32);     \
        xr = *(const f32x4*)xp;                                          \
    }

#define COMMIT(ph, buf, wr0, wr1, xr)                                    \
    {   ((bf16x8*)wLds[buf])[t]        = wr0;                            \
        ((bf16x8*)wLds[buf])[t + 1024] = wr1;                            \
        f32x4 y = xr;                                                    \
        if ((ph) < 16) {                                                 \
            _Pragma("unroll")                                            \
            for (int i = 0; i < 4; ++i) y[i] = (y[i] - muR) * rsR;       \
        }                                                                \
        bf16x4 xv;                                                       \
        _Pragma("unroll")                                                \
        for (int i = 0; i < 4; ++i) xv[i] = (short)f2bf(y[i]);           \
        *(bf16x4*)((char*)xLds[buf] + xByte) = xv;                       \
    }

    {   bf16x8 wr0, wr1; f32x4 xr;
        ISSUE(0, wr0, wr1, xr);
        COMMIT(0, 0, wr0, wr1, xr);
    }
    __syncthreads();

    for (int ph = 0; ph < 32; ++ph) {
        const int cur = ph & 1;
        bf16x8 wr0, wr1; f32x4 xr;
        if (ph < 31) ISSUE(ph + 1, wr0, wr1, xr);

        // MFMA cluster from LDS buf[cur]
        bf16x8 wf0 = ((const bf16x8*)wLds[cur])[(wn * 4 + 0) * 64 + lane];
        bf16x8 wf1 = ((const bf16x8*)wLds[cur])[(wn * 4 + 1) * 64 + lane];
        bf16x8 wf2 = ((const bf16x8*)wLds[cur])[(wn * 4 + 2) * 64 + lane];
        bf16x8 wf3 = ((const bf16x8*)wLds[cur])[(wn * 4 + 3) * 64 + lane];
#pragma unroll
        for (int rt = 0; rt < 4; ++rt) {
            bf16x8 xf = ((const bf16x8*)xLds[cur])[(wm * 4 + rt) * 64 + lane];
            acc[rt][0] = __builtin_amdgcn_mfma_f32_16x16x32_bf16(wf0, xf, acc[rt][0], 0, 0, 0);
            acc[rt][1] = __builtin_amdgcn_mfma_f32_16x16x32_bf16(wf1, xf, acc[rt][1], 0, 0, 0);
            acc[rt][2] = __builtin_amdgcn_mfma_f32_16x16x32_bf16(wf2, xf, acc[rt][2], 0, 0, 0);
            acc[rt][3] = __builtin_amdgcn_mfma_f32_16x16x32_bf16(wf3, xf, acc[rt][3], 0, 0, 0);
        }

        if (ph < 31) COMMIT(ph + 1, cur ^ 1, wr0, wr1, xr);
        __syncthreads();
    }
#undef ISSUE
#undef COMMIT

    // ---- epilogue: bias+sigmoid+fuse; emb/slow re-read (L3-hot); f32x4 out ----
#pragma unroll
    for (int rt = 0; rt < 4; ++rt) {
        int rowl = wm * 64 + rt * 16 + (lane & 15);
        int grow = brow + rowl;
        int id   = idS[rowl];
        float mu = muS[rowl], rs = rsS[rowl], act = actS[rowl];
        const float* embP  = emb  + (size_t)grow * HDIM;
        const float* slowP = slow + (size_t)id * HDIM;
        float*       outP  = out  + (size_t)grow * HDIM;
#pragma unroll
        for (int ct = 0; ct < 4; ++ct) {
            int col0 = wn * 64 + ct * 16 + ((lane >> 4) << 2);
            f32x4 bv = *(const f32x4*)&bS[col0];
            f32x4 ev = *(const f32x4*)(embP + col0);
            f32x4 sv = *(const f32x4*)(slowP + col0);
            f32x4 o;
#pragma unroll
            for (int r = 0; r < 4; ++r) {
                float logit = acc[rt][ct][r] + bv[r];
                float z  = 1.f / (1.f + __expf(-logit));
                float h  = (sv[r] - mu) * rs;
                float fused = z * ev[r] + (1.f - z) * h;
                o[r] = (act > 0.f) ? fused : ev[r];
            }
            *(f32x4*)(outP + col0) = o;
        }
    }
}

// Per-entity: gather its rows from `out` (CSR), mean -> EMA fast, norm-gated slow.
__global__ __launch_bounds__(256) void finalize_kernel(
    const float* __restrict__ fast, const float* __restrict__ slow,
    const float* __restrict__ out, const unsigned* __restrict__ off,
    const int* __restrict__ rowidx, float* __restrict__ nf, float* __restrict__ ns)
{
    int e = blockIdx.x * 4 + (threadIdx.x >> 6);
    if (e >= NENT) return;
    int lane = threadIdx.x & 63;
    size_t base = (size_t)e * HDIM + lane * 8;

    f32x4 f0 = *(const f32x4*)(fast + base), f1 = *(const f32x4*)(fast + base + 4);
    f32x4 l0 = *(const f32x4*)(slow + base), l1 = *(const f32x4*)(slow + base + 4);

    unsigned o0 = off[e], o1 = off[e + 1];
    int c = (int)(o1 - o0);

    if (c == 0) {
        *(f32x4*)(nf + base)     = f0;
        *(f32x4*)(nf + base + 4) = f1;
        *(f32x4*)(ns + base)     = l0;
        *(f32x4*)(ns + base + 4) = l1;
        return;
    }

    f32x4 s0 = {0.f, 0.f, 0.f, 0.f}, s1 = {0.f, 0.f, 0.f, 0.f};
    for (int j = 0; j < c; ++j) {
        int r = rowidx[o0 + j];
        const float* p = out + (size_t)r * HDIM + lane * 8;
        s0 += *(const f32x4*)p;
        s1 += *(const f32x4*)(p + 4);
    }

    float inv = 0.5f / (float)c;          // ALPHA / count
    f32x4 n0, n1, d0, d1;
    float ss = 0.f;
#pragma unroll
    for (int i = 0; i < 4; ++i) {
        n0[i] = 0.5f * f0[i] + s0[i] * inv;
        n1[i] = 0.5f * f1[i] + s1[i] * inv;
        d0[i] = n0[i] - l0[i]; ss += d0[i] * d0[i];
        d1[i] = n1[i] - l1[i]; ss += d1[i] * d1[i];
    }
#pragma unroll
    for (int m = 32; m >= 1; m >>= 1) ss += __shfl_xor(ss, m);
    float delta = sqrtf(ss);
    float gate  = 1.f / (1.f + expf(-5.f * (delta - 0.5f)));

    f32x4 o0v, o1v;
#pragma unroll
    for (int i = 0; i < 4; ++i) {
        o0v[i] = l0[i] + gate * d0[i];
        o1v[i] = l1[i] + gate * d1[i];
    }
    *(f32x4*)(nf + base)     = n0;
    *(f32x4*)(nf + base + 4) = n1;
    *(f32x4*)(ns + base)     = o0v;
    *(f32x4*)(ns + base + 4) = o1v;
}

extern "C" void kernel_launch(void* const* d_in, const int* in_sizes, int n_in,
                              void* d_out, int out_size, void* d_ws, size_t ws_size,
                              hipStream_t stream) {
    const float* emb  = (const float*)d_in[0];
    const float* slow = (const float*)d_in[1];
    const float* fast = (const float*)d_in[2];
    const float* W    = (const float*)d_in[3];
    const float* bias = (const float*)d_in[4];
    const int*   ids  = (const int*)d_in[5];

    float* out = (float*)d_out;
    float* nf  = out + (size_t)NROWS * HDIM;
    float* ns  = nf + (size_t)NENT * HDIM;

    // ws layout: Wp 1 MiB | counts/cursor 400 KB | offsets 400 KB | bsums | rowidx 1 MiB
    unsigned short* Wp   = (unsigned short*)d_ws;
    unsigned* counts     = (unsigned*)((char*)d_ws + (1u << 20));            // reused as cursor
    unsigned* off        = (unsigned*)((char*)d_ws + (1u << 20) + 512 * 1024);
    unsigned* bsums      = (unsigned*)((char*)d_ws + (2u << 20));
    int*      rowidx     = (int*)((char*)d_ws + (2u << 20) + 4096);

    hipMemsetAsync(counts, 0, (size_t)NENT * sizeof(unsigned), stream);

    pack_w_kernel<<<256, 256, 0, stream>>>(W, Wp);
    count_kernel<<<NROWS / 256, 256, 0, stream>>>(ids, counts);
    scan1_kernel<<<SCAN_NBLK, 1024, 0, stream>>>(counts, off, bsums);
    scan2_kernel<<<1, 64, 0, stream>>>(bsums);
    scan3_kernel<<<SCAN_NBLK, 1024, 0, stream>>>(off, bsums, counts);
    fill_kernel<<<NROWS / 256, 256, 0, stream>>>(ids, counts, rowidx);
    fuse_kernel<<<NROWS / 128, 1024, 0, stream>>>(emb, slow, Wp, bias, ids, out);
    finalize_kernel<<<(NENT + 3) / 4, 256, 0, stream>>>(fast, slow, out, off, rowidx, nf, ns);
}

// Round 9
// 1029.324 us; speedup vs baseline: 1.4212x; 1.0025x over previous
//
#include <hip/hip_runtime.h>
#include <hip/hip_bf16.h>
#include <cstdint>

#define NROWS 262144
#define HDIM  512
#define NENT  100000
#define SCAN_NBLK ((NENT + 1023) / 1024)

typedef __attribute__((ext_vector_type(4))) float  f32x4;
typedef __attribute__((ext_vector_type(8))) short  bf16x8;
typedef __attribute__((ext_vector_type(4))) short  bf16x4;

static __device__ __forceinline__ unsigned short f2bf(float x) {
    unsigned u = __float_as_uint(x);
    u += 0x7FFF + ((u >> 16) & 1);          // round-to-nearest-even
    return (unsigned short)(u >> 16);
}

// async global->LDS, 16B per lane; LDS dest must be wave-uniform base + lane*16
static __device__ __forceinline__ void gll16(const void* g, void* l) {
    __builtin_amdgcn_global_load_lds(
        (const __attribute__((address_space(1))) unsigned int*)g,
        (__attribute__((address_space(3))) unsigned int*)l, 16, 0, 0);
}

// Pack W ([512][1024] row-major, y = x @ W.T) into PHASE-MAJOR MFMA A-frag
// order: Wp[kt][nt][lane] (bf16x8). Lane l of frag (nt,kt) holds
// A[m = nt*16+(l&15)][k = kt*32+(l>>4)*8+j]. One kt-slice = 32 KB contiguous,
// laid out exactly as the fuse kernel's LDS image (linear -> global_load_lds).
__global__ void pack_w_kernel(const float* __restrict__ W, unsigned short* __restrict__ Wp) {
    int g    = blockIdx.x * 256 + threadIdx.x;   // 65536 slots
    int lane = g & 63;
    int nt   = (g >> 6) & 31;
    int kt   = g >> 11;
    int col  = nt * 16 + (lane & 15);
    int k    = kt * 32 + ((lane >> 4) << 3);
    const float* src = W + (size_t)col * 1024 + k;
    f32x4 v0 = *(const f32x4*)(src);
    f32x4 v1 = *(const f32x4*)(src + 4);
    bf16x8 ov;
#pragma unroll
    for (int i = 0; i < 4; ++i) {
        ov[i]     = (short)f2bf(v0[i]);
        ov[4 + i] = (short)f2bf(v1[i]);
    }
    *(bf16x8*)(Wp + (size_t)g * 8) = ov;
}

// ---- CSR build: counts -> 2-level exclusive scan -> fill row indices ----
__global__ __launch_bounds__(256) void count_kernel(const int* __restrict__ ids,
                                                    unsigned* __restrict__ counts) {
    int r = blockIdx.x * 256 + threadIdx.x;
    if (r < NROWS) atomicAdd(&counts[ids[r]], 1u);
}

__global__ __launch_bounds__(1024) void scan1_kernel(const unsigned* __restrict__ counts,
                                                     unsigned* __restrict__ off,
                                                     unsigned* __restrict__ bsums) {
    __shared__ unsigned tmp[1024];
    int i = blockIdx.x * 1024 + threadIdx.x;
    unsigned v = (i < NENT) ? counts[i] : 0u;
    tmp[threadIdx.x] = v;
    __syncthreads();
#pragma unroll
    for (int o = 1; o < 1024; o <<= 1) {
        unsigned a = (threadIdx.x >= o) ? tmp[threadIdx.x - o] : 0u;
        __syncthreads();
        tmp[threadIdx.x] += a;
        __syncthreads();
    }
    if (i < NENT) off[i] = tmp[threadIdx.x] - v;     // block-local exclusive
    if (threadIdx.x == 1023) bsums[blockIdx.x] = tmp[1023];
}

__global__ void scan2_kernel(unsigned* __restrict__ bsums) {
    if (threadIdx.x == 0 && blockIdx.x == 0) {
        unsigned s = 0;
        for (int i = 0; i < SCAN_NBLK; ++i) { unsigned t = bsums[i]; bsums[i] = s; s += t; }
    }
}

__global__ __launch_bounds__(1024) void scan3_kernel(unsigned* __restrict__ off,
                                                     const unsigned* __restrict__ bsums,
                                                     unsigned* __restrict__ cursor) {
    int i = blockIdx.x * 1024 + threadIdx.x;
    if (i < NENT) {
        unsigned o = off[i] + bsums[blockIdx.x];
        off[i] = o;
        cursor[i] = o;
    }
    if (i == 0) off[NENT] = NROWS;
}

__global__ __launch_bounds__(256) void fill_kernel(const int* __restrict__ ids,
                                                   unsigned* __restrict__ cursor,
                                                   int* __restrict__ rowidx) {
    int r = blockIdx.x * 256 + threadIdx.x;
    if (r < NROWS) {
        unsigned p = atomicAdd(&cursor[ids[r]], 1u);
        rowidx[p] = r;
    }
}

// Fused gate path v6 (m97-style): 512 thr = 8 waves; BM=64 rows, BN=512 cols,
// BK=32. Wave = 64r x 64c, acc 4x4. W staged per step via global_load_lds
// (single-buffered 32 KB, linear dest); x reg->pack->LDS double-buffered
// (2x4 KB). 2 barriers/step; ~44 KB LDS -> 2 blocks/CU so one block's
// barrier drain overlaps the other's MFMA. K-order: phases 0..15 = LN(state)
// (W kt 16..31), 16..31 = emb (W kt 0..15) -> emb L2-warm for epilogue.
__global__ __launch_bounds__(512, 4) void fuse_kernel(
    const float* __restrict__ emb, const float* __restrict__ slow,
    const unsigned short* __restrict__ Wp, const float* __restrict__ bias,
    const int* __restrict__ ids, float* __restrict__ out)
{
    __shared__ unsigned short wT[2048 * 8];      // 32 KB: 32 nt-frags x 64 lanes x 16B
    __shared__ unsigned short xT[2][256 * 8];    // 2 x 4 KB: 4 rt-frags x 64 lanes x 16B
    __shared__ float muS[64], rsS[64], actS[64], bS[512];
    __shared__ int idS[64];

    const int t    = threadIdx.x;
    const int w    = t >> 6;          // 0..7
    const int lane = t & 63;
    const int brow = blockIdx.x * 64;

    if (t < 128) ((f32x4*)bS)[t] = ((const f32x4*)bias)[t];

    // ---- LN stats + is_active: 8 waves x 8 rows ----
    for (int rr = 0; rr < 8; ++rr) {
        int row = w * 8 + rr;
        int id  = ids[brow + row];
        const float* sp = slow + (size_t)id * HDIM;
        f32x4 v0 = ((const f32x4*)sp)[lane * 2];
        f32x4 v1 = ((const f32x4*)sp)[lane * 2 + 1];
        float s = 0.f, s2 = 0.f, sa = 0.f;
#pragma unroll
        for (int i = 0; i < 4; ++i) {
            s  += v0[i] + v1[i];
            s2 += v0[i] * v0[i] + v1[i] * v1[i];
            sa += fabsf(v0[i]) + fabsf(v1[i]);
        }
#pragma unroll
        for (int m = 32; m >= 1; m >>= 1) {
            s  += __shfl_xor(s, m);
            s2 += __shfl_xor(s2, m);
            sa += __shfl_xor(sa, m);
        }
        if (lane == 0) {
            float mu  = s * (1.f / HDIM);
            float var = s2 * (1.f / HDIM) - mu * mu;
            muS[row]  = mu;
            rsS[row]  = rsqrtf(var + 1e-5f);
            actS[row] = (sa > 1e-6f) ? 1.f : 0.f;
            idS[row]  = id;
        }
    }
    __syncthreads();

    // ---- x staging geometry: thread t covers row = t>>3, k4 = (t&7)*4 ----
    const int xrow = t >> 3;
    const int k4   = (t & 7) * 4;
    const float* srcSt = slow + (size_t)idS[xrow] * HDIM + k4;
    const float* srcEm = emb + (size_t)(brow + xrow) * HDIM + k4;
    const float muR = muS[xrow], rsR = rsS[xrow];
    // x LDS byte: frag rt = xrow>>4, lane = ((k4>>3)<<4)|(xrow&15), sub = (k4&7)*2
    const int xByte = (((xrow >> 4) * 64 + (((k4 >> 3) << 4) | (xrow & 15))) << 4) + ((k4 & 7) << 1);

    f32x4 zero4 = {0.f, 0.f, 0.f, 0.f};
    f32x4 acc[4][4];                  // [rt = x-row tile][ct = gate-col tile]
#pragma unroll
    for (int i = 0; i < 4; ++i)
#pragma unroll
        for (int j = 0; j < 4; ++j) acc[i][j] = zero4;

#define LOAD_X(ph, xr)                                                   \
    {   const float* p = ((ph) < 16) ? (srcSt + (ph) * 32)               \
                                     : (srcEm + ((ph) - 16) * 32);       \
        xr = *(const f32x4*)p;                                           \
    }

    f32x4 xr;
    LOAD_X(0, xr);

    for (int ph = 0; ph < 32; ++ph) {
        const int cur = ph & 1;
        if (ph) __syncthreads();           // compute(ph-1) done: wT/xT[cur] safe

        // ---- stage phase ----
        // x: LN (state phases), pack, ds_write into xT[cur]
        {
            f32x4 y = xr;
            if (ph < 16) {
#pragma unroll
                for (int i = 0; i < 4; ++i) y[i] = (y[i] - muR) * rsR;
            }
            bf16x4 xv;
#pragma unroll
            for (int i = 0; i < 4; ++i) xv[i] = (short)f2bf(y[i]);
            *(bf16x4*)((char*)xT[cur] + xByte) = xv;
        }
        // W: async DMA the 32 KB kt-slice into wT (linear; 4 x 16B per thread)
        {
            const int ktW = (ph < 16) ? (16 + ph) : (ph - 16);
            const unsigned short* wsrc = Wp + (size_t)ktW * 16384;
#pragma unroll
            for (int i = 0; i < 4; ++i)
                gll16(wsrc + (size_t)(i * 512 + t) * 8,
                      (char*)wT + i * 8192 + w * 1024 + lane * 16);
        }
        __syncthreads();                   // drains vmcnt (gll) + lgkm (ds_write)

        // issue next x loads; they drain at the next loop-top barrier
        if (ph < 31) LOAD_X(ph + 1, xr);

        // ---- compute phase: wave w -> cols w*64..+63 ----
        bf16x8 wf0 = *(const bf16x8*)((char*)wT + ((w * 4 + 0) * 64 + lane) * 16);
        bf16x8 wf1 = *(const bf16x8*)((char*)wT + ((w * 4 + 1) * 64 + lane) * 16);
        bf16x8 wf2 = *(const bf16x8*)((char*)wT + ((w * 4 + 2) * 64 + lane) * 16);
        bf16x8 wf3 = *(const bf16x8*)((char*)wT + ((w * 4 + 3) * 64 + lane) * 16);
#pragma unroll
        for (int rt = 0; rt < 4; ++rt) {
            bf16x8 xf = *(const bf16x8*)((char*)xT[cur] + ((rt * 64 + lane) * 16));
            acc[rt][0] = __builtin_amdgcn_mfma_f32_16x16x32_bf16(wf0, xf, acc[rt][0], 0, 0, 0);
            acc[rt][1] = __builtin_amdgcn_mfma_f32_16x16x32_bf16(wf1, xf, acc[rt][1], 0, 0, 0);
            acc[rt][2] = __builtin_amdgcn_mfma_f32_16x16x32_bf16(wf2, xf, acc[rt][2], 0, 0, 0);
            acc[rt][3] = __builtin_amdgcn_mfma_f32_16x16x32_bf16(wf3, xf, acc[rt][3], 0, 0, 0);
        }
    }
#undef LOAD_X

    // ---- epilogue: bias+sigmoid+fuse; emb/slow re-read; f32x4 out ----
#pragma unroll
    for (int rt = 0; rt < 4; ++rt) {
        int rowl = rt * 16 + (lane & 15);
        int grow = brow + rowl;
        int id   = idS[rowl];
        float mu = muS[rowl], rs = rsS[rowl], act = actS[rowl];
        const float* embP  = emb  + (size_t)grow * HDIM;
        const float* slowP = slow + (size_t)id * HDIM;
        float*       outP  = out  + (size_t)grow * HDIM;
#pragma unroll
        for (int ct = 0; ct < 4; ++ct) {
            int col0 = w * 64 + ct * 16 + ((lane >> 4) << 2);
            f32x4 bv = *(const f32x4*)&bS[col0];
            f32x4 ev = *(const f32x4*)(embP + col0);
            f32x4 sv = *(const f32x4*)(slowP + col0);
            f32x4 o;
#pragma unroll
            for (int r = 0; r < 4; ++r) {
                float logit = acc[rt][ct][r] + bv[r];
                float z  = 1.f / (1.f + __expf(-logit));
                float h  = (sv[r] - mu) * rs;
                float fused = z * ev[r] + (1.f - z) * h;
                o[r] = (act > 0.f) ? fused : ev[r];
            }
            *(f32x4*)(outP + col0) = o;
        }
    }
}

// Per-entity: gather its rows from `out` (CSR), mean -> EMA fast, norm-gated slow.
__global__ __launch_bounds__(256) void finalize_kernel(
    const float* __restrict__ fast, const float* __restrict__ slow,
    const float* __restrict__ out, const unsigned* __restrict__ off,
    const int* __restrict__ rowidx, float* __restrict__ nf, float* __restrict__ ns)
{
    int e = blockIdx.x * 4 + (threadIdx.x >> 6);
    if (e >= NENT) return;
    int lane = threadIdx.x & 63;
    size_t base = (size_t)e * HDIM + lane * 8;

    f32x4 f0 = *(const f32x4*)(fast + base), f1 = *(const f32x4*)(fast + base + 4);
    f32x4 l0 = *(const f32x4*)(slow + base), l1 = *(const f32x4*)(slow + base + 4);

    unsigned o0 = off[e], o1 = off[e + 1];
    int c = (int)(o1 - o0);

    if (c == 0) {
        *(f32x4*)(nf + base)     = f0;
        *(f32x4*)(nf + base + 4) = f1;
        *(f32x4*)(ns + base)     = l0;
        *(f32x4*)(ns + base + 4) = l1;
        return;
    }

    f32x4 s0 = {0.f, 0.f, 0.f, 0.f}, s1 = {0.f, 0.f, 0.f, 0.f};
    for (int j = 0; j < c; ++j) {
        int r = rowidx[o0 + j];
        const float* p = out + (size_t)r * HDIM + lane * 8;
        s0 += *(const f32x4*)p;
        s1 += *(const f32x4*)(p + 4);
    }

    float inv = 0.5f / (float)c;          // ALPHA / count
    f32x4 n0, n1, d0, d1;
    float ss = 0.f;
#pragma unroll
    for (int i = 0; i < 4; ++i) {
        n0[i] = 0.5f * f0[i] + s0[i] * inv;
        n1[i] = 0.5f * f1[i] + s1[i] * inv;
        d0[i] = n0[i] - l0[i]; ss += d0[i] * d0[i];
        d1[i] = n1[i] - l1[i]; ss += d1[i] * d1[i];
    }
#pragma unroll
    for (int m = 32; m >= 1; m >>= 1) ss += __shfl_xor(ss, m);
    float delta = sqrtf(ss);
    float gate  = 1.f / (1.f + expf(-5.f * (delta - 0.5f)));

    f32x4 o0v, o1v;
#pragma unroll
    for (int i = 0; i < 4; ++i) {
        o0v[i] = l0[i] + gate * d0[i];
        o1v[i] = l1[i] + gate * d1[i];
    }
    *(f32x4*)(nf + base)     = n0;
    *(f32x4*)(nf + base + 4) = n1;
    *(f32x4*)(ns + base)     = o0v;
    *(f32x4*)(ns + base + 4) = o1v;
}

extern "C" void kernel_launch(void* const* d_in, const int* in_sizes, int n_in,
                              void* d_out, int out_size, void* d_ws, size_t ws_size,
                              hipStream_t stream) {
    const float* emb  = (const float*)d_in[0];
    const float* slow = (const float*)d_in[1];
    const float* fast = (const float*)d_in[2];
    const float* W    = (const float*)d_in[3];
    const float* bias = (const float*)d_in[4];
    const int*   ids  = (const int*)d_in[5];

    float* out = (float*)d_out;
    float* nf  = out + (size_t)NROWS * HDIM;
    float* ns  = nf + (size_t)NENT * HDIM;

    // ws layout: Wp 1 MiB | counts/cursor 400 KB | offsets 400 KB | bsums | rowidx 1 MiB
    unsigned short* Wp   = (unsigned short*)d_ws;
    unsigned* counts     = (unsigned*)((char*)d_ws + (1u << 20));            // reused as cursor
    unsigned* off        = (unsigned*)((char*)d_ws + (1u << 20) + 512 * 1024);
    unsigned* bsums      = (unsigned*)((char*)d_ws + (2u << 20));
    int*      rowidx     = (int*)((char*)d_ws + (2u << 20) + 4096);

    hipMemsetAsync(counts, 0, (size_t)NENT * sizeof(unsigned), stream);

    pack_w_kernel<<<256, 256, 0, stream>>>(W, Wp);
    count_kernel<<<NROWS / 256, 256, 0, stream>>>(ids, counts);
    scan1_kernel<<<SCAN_NBLK, 1024, 0, stream>>>(counts, off, bsums);
    scan2_kernel<<<1, 64, 0, stream>>>(bsums);
    scan3_kernel<<<SCAN_NBLK, 1024, 0, stream>>>(off, bsums, counts);
    fill_kernel<<<NROWS / 256, 256, 0, stream>>>(ids, counts, rowidx);
    fuse_kernel<<<NROWS / 64, 512, 0, stream>>>(emb, slow, Wp, bias, ids, out);
    finalize_kernel<<<(NENT + 3) / 4, 256, 0, stream>>>(fast, slow, out, off, rowidx, nf, ns);
}

// Round 10
// 989.062 us; speedup vs baseline: 1.4790x; 1.0407x over previous
//
#include <hip/hip_runtime.h>
#include <hip/hip_bf16.h>
#include <cstdint>

#define NROWS 262144
#define HDIM  512
#define NENT  100000
#define SCAN_NBLK ((NENT + 1023) / 1024)

typedef __attribute__((ext_vector_type(4))) float  f32x4;
typedef __attribute__((ext_vector_type(8))) short  bf16x8;
typedef __attribute__((ext_vector_type(4))) short  bf16x4;

static __device__ __forceinline__ unsigned short f2bf(float x) {
    unsigned u = __float_as_uint(x);
    u += 0x7FFF + ((u >> 16) & 1);          // round-to-nearest-even
    return (unsigned short)(u >> 16);
}

// async global->LDS, 16B per lane; LDS dest must be wave-uniform base + lane*16
static __device__ __forceinline__ void gll16(const void* g, void* l) {
    __builtin_amdgcn_global_load_lds(
        (const __attribute__((address_space(1))) unsigned int*)g,
        (__attribute__((address_space(3))) unsigned int*)l, 16, 0, 0);
}

// Pack W ([512][1024] row-major, y = x @ W.T) into PHASE-MAJOR MFMA A-frag
// order: Wp[kt][nt][lane] (bf16x8). Lane l of frag (nt,kt) holds
// A[m = nt*16+(l&15)][k = kt*32+(l>>4)*8+j]. One kt-slice = 32 KB contiguous,
// laid out exactly as the fuse kernel's LDS image (linear -> global_load_lds).
__global__ void pack_w_kernel(const float* __restrict__ W, unsigned short* __restrict__ Wp) {
    int g    = blockIdx.x * 256 + threadIdx.x;   // 65536 slots
    int lane = g & 63;
    int nt   = (g >> 6) & 31;
    int kt   = g >> 11;
    int col  = nt * 16 + (lane & 15);
    int k    = kt * 32 + ((lane >> 4) << 3);
    const float* src = W + (size_t)col * 1024 + k;
    f32x4 v0 = *(const f32x4*)(src);
    f32x4 v1 = *(const f32x4*)(src + 4);
    bf16x8 ov;
#pragma unroll
    for (int i = 0; i < 4; ++i) {
        ov[i]     = (short)f2bf(v0[i]);
        ov[4 + i] = (short)f2bf(v1[i]);
    }
    *(bf16x8*)(Wp + (size_t)g * 8) = ov;
}

// ---- CSR build: counts -> 2-level exclusive scan -> fill row indices ----
__global__ __launch_bounds__(256) void count_kernel(const int* __restrict__ ids,
                                                    unsigned* __restrict__ counts) {
    int r = blockIdx.x * 256 + threadIdx.x;
    if (r < NROWS) atomicAdd(&counts[ids[r]], 1u);
}

__global__ __launch_bounds__(1024) void scan1_kernel(const unsigned* __restrict__ counts,
                                                     unsigned* __restrict__ off,
                                                     unsigned* __restrict__ bsums) {
    __shared__ unsigned tmp[1024];
    int i = blockIdx.x * 1024 + threadIdx.x;
    unsigned v = (i < NENT) ? counts[i] : 0u;
    tmp[threadIdx.x] = v;
    __syncthreads();
#pragma unroll
    for (int o = 1; o < 1024; o <<= 1) {
        unsigned a = (threadIdx.x >= o) ? tmp[threadIdx.x - o] : 0u;
        __syncthreads();
        tmp[threadIdx.x] += a;
        __syncthreads();
    }
    if (i < NENT) off[i] = tmp[threadIdx.x] - v;     // block-local exclusive
    if (threadIdx.x == 1023) bsums[blockIdx.x] = tmp[1023];
}

__global__ void scan2_kernel(unsigned* __restrict__ bsums) {
    if (threadIdx.x == 0 && blockIdx.x == 0) {
        unsigned s = 0;
        for (int i = 0; i < SCAN_NBLK; ++i) { unsigned t = bsums[i]; bsums[i] = s; s += t; }
    }
}

__global__ __launch_bounds__(1024) void scan3_kernel(unsigned* __restrict__ off,
                                                     const unsigned* __restrict__ bsums,
                                                     unsigned* __restrict__ cursor) {
    int i = blockIdx.x * 1024 + threadIdx.x;
    if (i < NENT) {
        unsigned o = off[i] + bsums[blockIdx.x];
        off[i] = o;
        cursor[i] = o;
    }
    if (i == 0) off[NENT] = NROWS;
}

__global__ __launch_bounds__(256) void fill_kernel(const int* __restrict__ ids,
                                                   unsigned* __restrict__ cursor,
                                                   int* __restrict__ rowidx) {
    int r = blockIdx.x * 256 + threadIdx.x;
    if (r < NROWS) {
        unsigned p = atomicAdd(&cursor[ids[r]], 1u);
        rowidx[p] = r;
    }
}

// Fused gate path v7: v6 geometry (512 thr = 8 waves; BM=64, BN=512, BK=32;
// wave = 64r x 64c, acc 4x4) with corrected pipelining:
//  - W DOUBLE-buffered via global_load_lds, issued at phase TOP (DMA flies
//    under this phase's 32 MFMAs; barrier drain is post-compute).
//  - x loaded TWO phases ahead (named ping-pong regs xA/xB).
//  - ONE barrier per phase.
// K-order: phases 0..15 = LN(state) (W kt 16..31), 16..31 = emb (W kt 0..15).
__global__ __launch_bounds__(512, 4) void fuse_kernel(
    const float* __restrict__ emb, const float* __restrict__ slow,
    const unsigned short* __restrict__ Wp, const float* __restrict__ bias,
    const int* __restrict__ ids, float* __restrict__ out)
{
    __shared__ unsigned short wT[2][2048 * 8];   // 2 x 32 KB
    __shared__ unsigned short xT[2][256 * 8];    // 2 x 4 KB
    __shared__ float muS[64], rsS[64], actS[64], bS[512];
    __shared__ int idS[64];

    const int t    = threadIdx.x;
    const int w    = t >> 6;          // 0..7
    const int lane = t & 63;
    const int brow = blockIdx.x * 64;

    if (t < 128) ((f32x4*)bS)[t] = ((const f32x4*)bias)[t];

    // ---- LN stats + is_active: 8 waves x 8 rows ----
    for (int rr = 0; rr < 8; ++rr) {
        int row = w * 8 + rr;
        int id  = ids[brow + row];
        const float* sp = slow + (size_t)id * HDIM;
        f32x4 v0 = ((const f32x4*)sp)[lane * 2];
        f32x4 v1 = ((const f32x4*)sp)[lane * 2 + 1];
        float s = 0.f, s2 = 0.f, sa = 0.f;
#pragma unroll
        for (int i = 0; i < 4; ++i) {
            s  += v0[i] + v1[i];
            s2 += v0[i] * v0[i] + v1[i] * v1[i];
            sa += fabsf(v0[i]) + fabsf(v1[i]);
        }
#pragma unroll
        for (int m = 32; m >= 1; m >>= 1) {
            s  += __shfl_xor(s, m);
            s2 += __shfl_xor(s2, m);
            sa += __shfl_xor(sa, m);
        }
        if (lane == 0) {
            float mu  = s * (1.f / HDIM);
            float var = s2 * (1.f / HDIM) - mu * mu;
            muS[row]  = mu;
            rsS[row]  = rsqrtf(var + 1e-5f);
            actS[row] = (sa > 1e-6f) ? 1.f : 0.f;
            idS[row]  = id;
        }
    }
    __syncthreads();

    // ---- x staging geometry: thread t covers row = t>>3, k4 = (t&7)*4 ----
    const int xrow = t >> 3;
    const int k4   = (t & 7) * 4;
    const float* srcSt = slow + (size_t)idS[xrow] * HDIM + k4;
    const float* srcEm = emb + (size_t)(brow + xrow) * HDIM + k4;
    const float muR = muS[xrow], rsR = rsS[xrow];
    const int xByte = (((xrow >> 4) * 64 + (((k4 >> 3) << 4) | (xrow & 15))) << 4) + ((k4 & 7) << 1);

    f32x4 zero4 = {0.f, 0.f, 0.f, 0.f};
    f32x4 acc[4][4];                  // [rt = x-row tile][ct = gate-col tile]
#pragma unroll
    for (int i = 0; i < 4; ++i)
#pragma unroll
        for (int j = 0; j < 4; ++j) acc[i][j] = zero4;

#define LOAD_X(ph, xr)                                                   \
    {   const float* p = ((ph) < 16) ? (srcSt + (ph) * 32)               \
                                     : (srcEm + ((ph) - 16) * 32);       \
        xr = *(const f32x4*)p;                                           \
    }
#define PACK_X(ph, xr, buf)                                              \
    {   f32x4 y = xr;                                                    \
        if ((ph) < 16) {                                                 \
            _Pragma("unroll")                                            \
            for (int i = 0; i < 4; ++i) y[i] = (y[i] - muR) * rsR;       \
        }                                                                \
        bf16x4 xv;                                                       \
        _Pragma("unroll")                                                \
        for (int i = 0; i < 4; ++i) xv[i] = (short)f2bf(y[i]);           \
        *(bf16x4*)((char*)xT[buf] + xByte) = xv;                         \
    }
#define GLL_W(ph, buf)                                                   \
    {   const int ktW = ((ph) < 16) ? (16 + (ph)) : ((ph) - 16);         \
        const unsigned short* wsrc = Wp + (size_t)ktW * 16384;           \
        _Pragma("unroll")                                                \
        for (int i = 0; i < 4; ++i)                                      \
            gll16(wsrc + (size_t)(i * 512 + t) * 8,                      \
                  (char*)wT[buf] + i * 8192 + w * 1024 + lane * 16);     \
    }

    // ---- prologue: stage phase 0; preload x(1) ----
    f32x4 xA, xB;
    GLL_W(0, 0);
    {   f32x4 x0; LOAD_X(0, x0); PACK_X(0, x0, 0); }
    LOAD_X(1, xA);
    __syncthreads();                      // drains gll(0) + ds_write

    for (int ph = 0; ph < 32; ++ph) {
        const int cur = ph & 1, nxt = cur ^ 1;

        // (1) prefetch W(ph+1): DMA flies under this phase's MFMAs
        if (ph < 31) GLL_W(ph + 1, nxt);
        // (2) x(ph+2), two phases ahead
        if (ph < 30) LOAD_X(ph + 2, xB);

        // (3) compute(ph)
        bf16x8 wf0 = *(const bf16x8*)((char*)wT[cur] + ((w * 4 + 0) * 64 + lane) * 16);
        bf16x8 wf1 = *(const bf16x8*)((char*)wT[cur] + ((w * 4 + 1) * 64 + lane) * 16);
        bf16x8 wf2 = *(const bf16x8*)((char*)wT[cur] + ((w * 4 + 2) * 64 + lane) * 16);
        bf16x8 wf3 = *(const bf16x8*)((char*)wT[cur] + ((w * 4 + 3) * 64 + lane) * 16);
#pragma unroll
        for (int rt = 0; rt < 4; ++rt) {
            bf16x8 xf = *(const bf16x8*)((char*)xT[cur] + ((rt * 64 + lane) * 16));
            acc[rt][0] = __builtin_amdgcn_mfma_f32_16x16x32_bf16(wf0, xf, acc[rt][0], 0, 0, 0);
            acc[rt][1] = __builtin_amdgcn_mfma_f32_16x16x32_bf16(wf1, xf, acc[rt][1], 0, 0, 0);
            acc[rt][2] = __builtin_amdgcn_mfma_f32_16x16x32_bf16(wf2, xf, acc[rt][2], 0, 0, 0);
            acc[rt][3] = __builtin_amdgcn_mfma_f32_16x16x32_bf16(wf3, xf, acc[rt][3], 0, 0, 0);
        }

        // (4) pack x(ph+1) (loaded last phase -> fully covered)
        if (ph < 31) PACK_X(ph + 1, xA, nxt);
        xA = xB;
        __syncthreads();                  // one barrier/phase: drain + publish
    }
#undef LOAD_X
#undef PACK_X
#undef GLL_W

    // ---- epilogue: bias+sigmoid+fuse; emb/slow re-read; f32x4 out ----
#pragma unroll
    for (int rt = 0; rt < 4; ++rt) {
        int rowl = rt * 16 + (lane & 15);
        int grow = brow + rowl;
        int id   = idS[rowl];
        float mu = muS[rowl], rs = rsS[rowl], act = actS[rowl];
        const float* embP  = emb  + (size_t)grow * HDIM;
        const float* slowP = slow + (size_t)id * HDIM;
        float*       outP  = out  + (size_t)grow * HDIM;
#pragma unroll
        for (int ct = 0; ct < 4; ++ct) {
            int col0 = w * 64 + ct * 16 + ((lane >> 4) << 2);
            f32x4 bv = *(const f32x4*)&bS[col0];
            f32x4 ev = *(const f32x4*)(embP + col0);
            f32x4 sv = *(const f32x4*)(slowP + col0);
            f32x4 o;
#pragma unroll
            for (int r = 0; r < 4; ++r) {
                float logit = acc[rt][ct][r] + bv[r];
                float z  = 1.f / (1.f + __expf(-logit));
                float h  = (sv[r] - mu) * rs;
                float fused = z * ev[r] + (1.f - z) * h;
                o[r] = (act > 0.f) ? fused : ev[r];
            }
            *(f32x4*)(outP + col0) = o;
        }
    }
}

// Per-entity: gather its rows from `out` (CSR), mean -> EMA fast, norm-gated slow.
__global__ __launch_bounds__(256) void finalize_kernel(
    const float* __restrict__ fast, const float* __restrict__ slow,
    const float* __restrict__ out, const unsigned* __restrict__ off,
    const int* __restrict__ rowidx, float* __restrict__ nf, float* __restrict__ ns)
{
    int e = blockIdx.x * 4 + (threadIdx.x >> 6);
    if (e >= NENT) return;
    int lane = threadIdx.x & 63;
    size_t base = (size_t)e * HDIM + lane * 8;

    f32x4 f0 = *(const f32x4*)(fast + base), f1 = *(const f32x4*)(fast + base + 4);
    f32x4 l0 = *(const f32x4*)(slow + base), l1 = *(const f32x4*)(slow + base + 4);

    unsigned o0 = off[e], o1 = off[e + 1];
    int c = (int)(o1 - o0);

    if (c == 0) {
        *(f32x4*)(nf + base)     = f0;
        *(f32x4*)(nf + base + 4) = f1;
        *(f32x4*)(ns + base)     = l0;
        *(f32x4*)(ns + base + 4) = l1;
        return;
    }

    f32x4 s0 = {0.f, 0.f, 0.f, 0.f}, s1 = {0.f, 0.f, 0.f, 0.f};
    for (int j = 0; j < c; ++j) {
        int r = rowidx[o0 + j];
        const float* p = out + (size_t)r * HDIM + lane * 8;
        s0 += *(const f32x4*)p;
        s1 += *(const f32x4*)(p + 4);
    }

    float inv = 0.5f / (float)c;          // ALPHA / count
    f32x4 n0, n1, d0, d1;
    float ss = 0.f;
#pragma unroll
    for (int i = 0; i < 4; ++i) {
        n0[i] = 0.5f * f0[i] + s0[i] * inv;
        n1[i] = 0.5f * f1[i] + s1[i] * inv;
        d0[i] = n0[i] - l0[i]; ss += d0[i] * d0[i];
        d1[i] = n1[i] - l1[i]; ss += d1[i] * d1[i];
    }
#pragma unroll
    for (int m = 32; m >= 1; m >>= 1) ss += __shfl_xor(ss, m);
    float delta = sqrtf(ss);
    float gate  = 1.f / (1.f + expf(-5.f * (delta - 0.5f)));

    f32x4 o0v, o1v;
#pragma unroll
    for (int i = 0; i < 4; ++i) {
        o0v[i] = l0[i] + gate * d0[i];
        o1v[i] = l1[i] + gate * d1[i];
    }
    *(f32x4*)(nf + base)     = n0;
    *(f32x4*)(nf + base + 4) = n1;
    *(f32x4*)(ns + base)     = o0v;
    *(f32x4*)(ns + base + 4) = o1v;
}

extern "C" void kernel_launch(void* const* d_in, const int* in_sizes, int n_in,
                              void* d_out, int out_size, void* d_ws, size_t ws_size,
                              hipStream_t stream) {
    const float* emb  = (const float*)d_in[0];
    const float* slow = (const float*)d_in[1];
    const float* fast = (const float*)d_in[2];
    const float* W    = (const float*)d_in[3];
    const float* bias = (const float*)d_in[4];
    const int*   ids  = (const int*)d_in[5];

    float* out = (float*)d_out;
    float* nf  = out + (size_t)NROWS * HDIM;
    float* ns  = nf + (size_t)NENT * HDIM;

    // ws layout: Wp 1 MiB | counts/cursor 400 KB | offsets 400 KB | bsums | rowidx 1 MiB
    unsigned short* Wp   = (unsigned short*)d_ws;
    unsigned* counts     = (unsigned*)((char*)d_ws + (1u << 20));            // reused as cursor
    unsigned* off        = (unsigned*)((char*)d_ws + (1u << 20) + 512 * 1024);
    unsigned* bsums      = (unsigned*)((char*)d_ws + (2u << 20));
    int*      rowidx     = (int*)((char*)d_ws + (2u << 20) + 4096);

    hipMemsetAsync(counts, 0, (size_t)NENT * sizeof(unsigned), stream);

    pack_w_kernel<<<256, 256, 0, stream>>>(W, Wp);
    count_kernel<<<NROWS / 256, 256, 0, stream>>>(ids, counts);
    scan1_kernel<<<SCAN_NBLK, 1024, 0, stream>>>(counts, off, bsums);
    scan2_kernel<<<1, 64, 0, stream>>>(bsums);
    scan3_kernel<<<SCAN_NBLK, 1024, 0, stream>>>(off, bsums, counts);
    fill_kernel<<<NROWS / 256, 256, 0, stream>>>(ids, counts, rowidx);
    fuse_kernel<<<NROWS / 64, 512, 0, stream>>>(emb, slow, Wp, bias, ids, out);
    finalize_kernel<<<(NENT + 3) / 4, 256, 0, stream>>>(fast, slow, out, off, rowidx, nf, ns);
}

// Round 11
// 986.448 us; speedup vs baseline: 1.4830x; 1.0027x over previous
//
#include <hip/hip_runtime.h>
#include <hip/hip_bf16.h>
#include <cstdint>

#define NROWS 262144
#define HDIM  512
#define NENT  100000
#define SCAN_NBLK ((NENT + 1023) / 1024)

typedef __attribute__((ext_vector_type(4))) float  f32x4;
typedef __attribute__((ext_vector_type(8))) short  bf16x8;
typedef __attribute__((ext_vector_type(4))) short  bf16x4;

static __device__ __forceinline__ unsigned short f2bf(float x) {
    unsigned u = __float_as_uint(x);
    u += 0x7FFF + ((u >> 16) & 1);          // round-to-nearest-even
    return (unsigned short)(u >> 16);
}
static __device__ __forceinline__ float bf2f(unsigned short h) {
    return __uint_as_float(((unsigned)h) << 16);
}

// Pack W ([512][1024], y = x@W.T) into TWO per-wave-linear bf16 A-frag arrays:
//   WeP = W[:, 0:512]   (emb half),  WsP = W[:, 512:1024] (state half)
// index gg = ((w*16 + kt)*4 + ct)*64 + lane ; nt = w*4+ct ;
// lane l of frag (nt,kt) holds A[m=nt*16+(l&15)][k=kt*32+(l>>4)*8+j].
__global__ void pack_w_kernel(const float* __restrict__ W,
                              unsigned short* __restrict__ WeP,
                              unsigned short* __restrict__ WsP) {
    int g    = blockIdx.x * 256 + threadIdx.x;   // 65536
    int sel  = g >> 15;
    int gg   = g & 32767;
    int lane = gg & 63;
    int ct   = (gg >> 6) & 3;
    int kt   = (gg >> 8) & 15;
    int w    = gg >> 12;
    int col  = (w * 4 + ct) * 16 + (lane & 15);
    int k    = kt * 32 + ((lane >> 4) << 3) + sel * 512;
    const float* src = W + (size_t)col * 1024 + k;
    f32x4 v0 = *(const f32x4*)(src);
    f32x4 v1 = *(const f32x4*)(src + 4);
    bf16x8 ov;
#pragma unroll
    for (int i = 0; i < 4; ++i) {
        ov[i]     = (short)f2bf(v0[i]);
        ov[4 + i] = (short)f2bf(v1[i]);
    }
    unsigned short* dst = sel ? WsP : WeP;
    *(bf16x8*)(dst + (size_t)gg * 8) = ov;
}

// ---- CSR build: counts -> 2-level exclusive scan -> fill row indices ----
__global__ __launch_bounds__(256) void count_kernel(const int* __restrict__ ids,
                                                    unsigned* __restrict__ counts) {
    int r = blockIdx.x * 256 + threadIdx.x;
    if (r < NROWS) atomicAdd(&counts[ids[r]], 1u);
}

__global__ __launch_bounds__(1024) void scan1_kernel(const unsigned* __restrict__ counts,
                                                     unsigned* __restrict__ off,
                                                     unsigned* __restrict__ bsums) {
    __shared__ unsigned tmp[1024];
    int i = blockIdx.x * 1024 + threadIdx.x;
    unsigned v = (i < NENT) ? counts[i] : 0u;
    tmp[threadIdx.x] = v;
    __syncthreads();
#pragma unroll
    for (int o = 1; o < 1024; o <<= 1) {
        unsigned a = (threadIdx.x >= o) ? tmp[threadIdx.x - o] : 0u;
        __syncthreads();
        tmp[threadIdx.x] += a;
        __syncthreads();
    }
    if (i < NENT) off[i] = tmp[threadIdx.x] - v;     // block-local exclusive
    if (threadIdx.x == 1023) bsums[blockIdx.x] = tmp[1023];
}

__global__ void scan2_kernel(unsigned* __restrict__ bsums) {
    if (threadIdx.x == 0 && blockIdx.x == 0) {
        unsigned s = 0;
        for (int i = 0; i < SCAN_NBLK; ++i) { unsigned t = bsums[i]; bsums[i] = s; s += t; }
    }
}

__global__ __launch_bounds__(1024) void scan3_kernel(unsigned* __restrict__ off,
                                                     const unsigned* __restrict__ bsums,
                                                     unsigned* __restrict__ cursor) {
    int i = blockIdx.x * 1024 + threadIdx.x;
    if (i < NENT) {
        unsigned o = off[i] + bsums[blockIdx.x];
        off[i] = o;
        cursor[i] = o;
    }
    if (i == 0) off[NENT] = NROWS;
}

__global__ __launch_bounds__(256) void fill_kernel(const int* __restrict__ ids,
                                                   unsigned* __restrict__ cursor,
                                                   int* __restrict__ rowidx) {
    int r = blockIdx.x * 256 + threadIdx.x;
    if (r < NROWS) {
        unsigned p = atomicAdd(&cursor[ids[r]], 1u);
        rowidx[p] = r;
    }
}

// Kernel A: per-entity precompute. 32 entities/block, 512 thr = 8 waves.
// h = LN(slow[e]) (coalesced, no gather); Gs = h @ Ws.T + b (K=512 GEMM,
// barrier-free loop, whole-K x in 32 KB LDS, Ws frags from L2 depth-2).
// Stores h, Gs as bf16; act flag as float. 100000 = 3125*32 exactly.
__global__ __launch_bounds__(512, 4) void entity_kernel(
    const float* __restrict__ slow, const unsigned short* __restrict__ WsP,
    const float* __restrict__ bias, unsigned short* __restrict__ hB,
    unsigned short* __restrict__ GsB, float* __restrict__ actB)
{
    __shared__ unsigned short xLds[2048 * 8];   // 32 KB: 32 tiles x 64 lanes x 16B
    __shared__ float muS[32], rsS[32], bS[512];

    const int t    = threadIdx.x;
    const int w    = t >> 6;          // 0..7
    const int lane = t & 63;
    const int brow = blockIdx.x * 32;

    if (t < 128) ((f32x4*)bS)[t] = ((const f32x4*)bias)[t];

    // ---- LN stats + is_active: 8 waves x 4 rows ----
    for (int rr = 0; rr < 4; ++rr) {
        int row = w * 4 + rr;
        int e   = brow + row;
        const float* sp = slow + (size_t)e * HDIM;
        f32x4 v0 = ((const f32x4*)sp)[lane * 2];
        f32x4 v1 = ((const f32x4*)sp)[lane * 2 + 1];
        float s = 0.f, s2 = 0.f, sa = 0.f;
#pragma unroll
        for (int i = 0; i < 4; ++i) {
            s  += v0[i] + v1[i];
            s2 += v0[i] * v0[i] + v1[i] * v1[i];
            sa += fabsf(v0[i]) + fabsf(v1[i]);
        }
#pragma unroll
        for (int m = 32; m >= 1; m >>= 1) {
            s  += __shfl_xor(s, m);
            s2 += __shfl_xor(s2, m);
            sa += __shfl_xor(sa, m);
        }
        if (lane == 0) {
            float mu  = s * (1.f / HDIM);
            float var = s2 * (1.f / HDIM) - mu * mu;
            muS[row] = mu;
            rsS[row] = rsqrtf(var + 1e-5f);
            actB[e]  = (sa > 1e-6f) ? 1.f : 0.f;
        }
    }
    __syncthreads();

    // ---- stage whole K=512 as LN(slow) bf16 fragments (4 slots/thread) ----
#pragma unroll
    for (int i = 0; i < 4; ++i) {
        int s  = t + i * 512;
        int T  = s >> 6, ls = s & 63;
        int row = (T & 1) * 16 + (ls & 15);
        int k   = (T >> 1) * 32 + ((ls >> 4) << 3);
        const float* p = slow + (size_t)(brow + row) * HDIM + k;
        f32x4 x0 = *(const f32x4*)p, x1 = *(const f32x4*)(p + 4);
        float mu = muS[row], rs = rsS[row];
        bf16x8 av;
#pragma unroll
        for (int j = 0; j < 4; ++j) {
            av[j]     = (short)f2bf((x0[j] - mu) * rs);
            av[4 + j] = (short)f2bf((x1[j] - mu) * rs);
        }
        ((bf16x8*)xLds)[s] = av;
    }
    __syncthreads();

    // ---- barrier-free K loop: wave w -> cols w*64..+63, depth-2 prefetch ----
    f32x4 zero4 = {0.f, 0.f, 0.f, 0.f};
    f32x4 acc[2][4];
#pragma unroll
    for (int i = 0; i < 2; ++i)
#pragma unroll
        for (int j = 0; j < 4; ++j) acc[i][j] = zero4;

    const unsigned short* wpW = WsP + (size_t)w * 32768 + (size_t)lane * 8;

#define LOADW(dst, kt)                                                  \
    {   _Pragma("unroll")                                               \
        for (int ct = 0; ct < 4; ++ct)                                  \
            dst[ct] = *(const bf16x8*)(wpW + ((kt) * 4 + ct) * 512);    \
    }
#define LOADX(dst, kt)                                                  \
    {   _Pragma("unroll")                                               \
        for (int rt = 0; rt < 2; ++rt)                                  \
            dst[rt] = ((const bf16x8*)xLds)[((kt) * 2 + rt) * 64 + lane]; \
    }
#define STEP(wf, xf)                                                    \
    {   _Pragma("unroll")                                               \
        for (int ct = 0; ct < 4; ++ct) {                                \
            acc[0][ct] = __builtin_amdgcn_mfma_f32_16x16x32_bf16(wf[ct], xf[0], acc[0][ct], 0, 0, 0); \
            acc[1][ct] = __builtin_amdgcn_mfma_f32_16x16x32_bf16(wf[ct], xf[1], acc[1][ct], 0, 0, 0); \
        }                                                               \
    }

    {
        bf16x8 wA[4], wB[4], xA[2], xB[2];
        LOADW(wA, 0); LOADX(xA, 0);
#pragma unroll
        for (int kt = 0; kt < 16; kt += 2) {
            if (kt + 1 < 16) { LOADW(wB, kt + 1); LOADX(xB, kt + 1); }
            STEP(wA, xA);
            if (kt + 2 < 16) { LOADW(wA, kt + 2); LOADX(xA, kt + 2); }
            if (kt + 1 < 16) STEP(wB, xB);
        }
    }

    // ---- epilogue: Gs = acc + b -> bf16; h from LDS -> bf16 ----
#pragma unroll
    for (int rt = 0; rt < 2; ++rt) {
        int e = brow + rt * 16 + (lane & 15);
#pragma unroll
        for (int ct = 0; ct < 4; ++ct) {
            int col0 = w * 64 + ct * 16 + ((lane >> 4) << 2);
            f32x4 bv = *(const f32x4*)&bS[col0];
            bf16x4 gv;
#pragma unroll
            for (int r = 0; r < 4; ++r) gv[r] = (short)f2bf(acc[rt][ct][r] + bv[r]);
            *(bf16x4*)(GsB + (size_t)e * HDIM + col0) = gv;
        }
    }
#pragma unroll
    for (int i = 0; i < 4; ++i) {
        int s  = t + i * 512;
        int T  = s >> 6, ls = s & 63;
        int row = (T & 1) * 16 + (ls & 15);
        int k   = (T >> 1) * 32 + ((ls >> 4) << 3);
        *(bf16x8*)(hB + (size_t)(brow + row) * HDIM + k) = ((const bf16x8*)xLds)[s];
    }
}

// Kernel B: row GEMM. 32 rows/block, 512 thr = 8 waves; z-logits =
// emb @ We.T (K=512, streaming, no gather/LN) ; epilogue gathers Gs[id]
// (includes bias), h[id], act[id] (bf16/f32, L3-resident) and blends.
__global__ __launch_bounds__(512, 4) void fuse_kernel(
    const float* __restrict__ emb, const unsigned short* __restrict__ WeP,
    const int* __restrict__ ids, const unsigned short* __restrict__ hB,
    const unsigned short* __restrict__ GsB, const float* __restrict__ actB,
    float* __restrict__ out)
{
    __shared__ unsigned short xLds[2048 * 8];   // 32 KB
    __shared__ int idS[32];

    const int t    = threadIdx.x;
    const int w    = t >> 6;
    const int lane = t & 63;
    const int brow = blockIdx.x * 32;

    if (t < 32) idS[t] = ids[brow + t];

    // ---- stage whole K=512 emb as bf16 fragments (4 slots/thread) ----
#pragma unroll
    for (int i = 0; i < 4; ++i) {
        int s  = t + i * 512;
        int T  = s >> 6, ls = s & 63;
        int row = (T & 1) * 16 + (ls & 15);
        int k   = (T >> 1) * 32 + ((ls >> 4) << 3);
        const float* p = emb + (size_t)(brow + row) * HDIM + k;
        f32x4 x0 = *(const f32x4*)p, x1 = *(const f32x4*)(p + 4);
        bf16x8 av;
#pragma unroll
        for (int j = 0; j < 4; ++j) {
            av[j]     = (short)f2bf(x0[j]);
            av[4 + j] = (short)f2bf(x1[j]);
        }
        ((bf16x8*)xLds)[s] = av;
    }
    __syncthreads();

    f32x4 zero4 = {0.f, 0.f, 0.f, 0.f};
    f32x4 acc[2][4];
#pragma unroll
    for (int i = 0; i < 2; ++i)
#pragma unroll
        for (int j = 0; j < 4; ++j) acc[i][j] = zero4;

    const unsigned short* wpW = WeP + (size_t)w * 32768 + (size_t)lane * 8;

    {
        bf16x8 wA[4], wB[4], xA[2], xB[2];
        LOADW(wA, 0); LOADX(xA, 0);
#pragma unroll
        for (int kt = 0; kt < 16; kt += 2) {
            if (kt + 1 < 16) { LOADW(wB, kt + 1); LOADX(xB, kt + 1); }
            STEP(wA, xA);
            if (kt + 2 < 16) { LOADW(wA, kt + 2); LOADX(xA, kt + 2); }
            if (kt + 1 < 16) STEP(wB, xB);
        }
    }
#undef LOADW
#undef LOADX
#undef STEP

    // ---- epilogue: z = sigmoid(acc + Gs[id]); out = act ? z*e+(1-z)*h : e ----
#pragma unroll
    for (int rt = 0; rt < 2; ++rt) {
        int rowl = rt * 16 + (lane & 15);
        int grow = brow + rowl;
        int id   = idS[rowl];
        float act = actB[id];
        const unsigned short* gsP = GsB + (size_t)id * HDIM;
        const unsigned short* hP  = hB  + (size_t)id * HDIM;
        float* outP = out + (size_t)grow * HDIM;
#pragma unroll
        for (int ct = 0; ct < 4; ++ct) {
            int col0 = w * 64 + ct * 16 + ((lane >> 4) << 2);
            // emb[row][col0..3] from LDS frag layout
            int Te = ((col0 >> 5) * 2 + rt) * 64 + (((col0 >> 3) & 3) << 4) + (lane & 15);
            const unsigned short* pe = xLds + Te * 8 + (col0 & 7);
            bf16x4 gv = *(const bf16x4*)(gsP + col0);
            bf16x4 hv = *(const bf16x4*)(hP + col0);
            f32x4 o;
#pragma unroll
            for (int r = 0; r < 4; ++r) {
                float ev = bf2f(pe[r]);
                float logit = acc[rt][ct][r] + bf2f(gv[r]);
                float z = 1.f / (1.f + __expf(-logit));
                float fused = z * ev + (1.f - z) * bf2f(hv[r]);
                o[r] = (act > 0.f) ? fused : ev;
            }
            *(f32x4*)(outP + col0) = o;
        }
    }
}

// Per-entity: gather its rows from `out` (CSR), mean -> EMA fast, norm-gated slow.
__global__ __launch_bounds__(256) void finalize_kernel(
    const float* __restrict__ fast, const float* __restrict__ slow,
    const float* __restrict__ out, const unsigned* __restrict__ off,
    const int* __restrict__ rowidx, float* __restrict__ nf, float* __restrict__ ns)
{
    int e = blockIdx.x * 4 + (threadIdx.x >> 6);
    if (e >= NENT) return;
    int lane = threadIdx.x & 63;
    size_t base = (size_t)e * HDIM + lane * 8;

    f32x4 f0 = *(const f32x4*)(fast + base), f1 = *(const f32x4*)(fast + base + 4);
    f32x4 l0 = *(const f32x4*)(slow + base), l1 = *(const f32x4*)(slow + base + 4);

    unsigned o0 = off[e], o1 = off[e + 1];
    int c = (int)(o1 - o0);

    if (c == 0) {
        *(f32x4*)(nf + base)     = f0;
        *(f32x4*)(nf + base + 4) = f1;
        *(f32x4*)(ns + base)     = l0;
        *(f32x4*)(ns + base + 4) = l1;
        return;
    }

    f32x4 s0 = {0.f, 0.f, 0.f, 0.f}, s1 = {0.f, 0.f, 0.f, 0.f};
    for (int j = 0; j < c; ++j) {
        int r = rowidx[o0 + j];
        const float* p = out + (size_t)r * HDIM + lane * 8;
        s0 += *(const f32x4*)p;
        s1 += *(const f32x4*)(p + 4);
    }

    float inv = 0.5f / (float)c;          // ALPHA / count
    f32x4 n0, n1, d0, d1;
    float ss = 0.f;
#pragma unroll
    for (int i = 0; i < 4; ++i) {
        n0[i] = 0.5f * f0[i] + s0[i] * inv;
        n1[i] = 0.5f * f1[i] + s1[i] * inv;
        d0[i] = n0[i] - l0[i]; ss += d0[i] * d0[i];
        d1[i] = n1[i] - l1[i]; ss += d1[i] * d1[i];
    }
#pragma unroll
    for (int m = 32; m >= 1; m >>= 1) ss += __shfl_xor(ss, m);
    float delta = sqrtf(ss);
    float gate  = 1.f / (1.f + expf(-5.f * (delta - 0.5f)));

    f32x4 o0v, o1v;
#pragma unroll
    for (int i = 0; i < 4; ++i) {
        o0v[i] = l0[i] + gate * d0[i];
        o1v[i] = l1[i] + gate * d1[i];
    }
    *(f32x4*)(nf + base)     = n0;
    *(f32x4*)(nf + base + 4) = n1;
    *(f32x4*)(ns + base)     = o0v;
    *(f32x4*)(ns + base + 4) = o1v;
}

extern "C" void kernel_launch(void* const* d_in, const int* in_sizes, int n_in,
                              void* d_out, int out_size, void* d_ws, size_t ws_size,
                              hipStream_t stream) {
    const float* emb  = (const float*)d_in[0];
    const float* slow = (const float*)d_in[1];
    const float* fast = (const float*)d_in[2];
    const float* W    = (const float*)d_in[3];
    const float* bias = (const float*)d_in[4];
    const int*   ids  = (const int*)d_in[5];

    float* out = (float*)d_out;
    float* nf  = out + (size_t)NROWS * HDIM;
    float* ns  = nf + (size_t)NENT * HDIM;

    // h/Gs (bf16, 102 MB each) live in the nf/ns regions until finalize
    // overwrites them (A writes -> B reads -> finalize writes).
    unsigned short* hB  = (unsigned short*)nf;
    unsigned short* GsB = (unsigned short*)ns;

    // ws: WeP 512K | WsP 512K | actB 400K | counts 400K | off 400K+4 | bsums | rowidx 1M
    unsigned short* WeP = (unsigned short*)d_ws;
    unsigned short* WsP = (unsigned short*)((char*)d_ws + (512u << 10));
    float* actB         = (float*)((char*)d_ws + (1024u << 10));
    unsigned* counts    = (unsigned*)((char*)d_ws + (1536u << 10));   // reused as cursor
    unsigned* off       = (unsigned*)((char*)d_ws + (2048u << 10));
    unsigned* bsums     = (unsigned*)((char*)d_ws + (2560u << 10));
    int*      rowidx    = (int*)((char*)d_ws + (2560u << 10) + 4096);

    hipMemsetAsync(counts, 0, (size_t)NENT * sizeof(unsigned), stream);

    pack_w_kernel<<<256, 256, 0, stream>>>(W, WeP, WsP);
    entity_kernel<<<NENT / 32, 512, 0, stream>>>(slow, WsP, bias, hB, GsB, actB);
    count_kernel<<<NROWS / 256, 256, 0, stream>>>(ids, counts);
    scan1_kernel<<<SCAN_NBLK, 1024, 0, stream>>>(counts, off, bsums);
    scan2_kernel<<<1, 64, 0, stream>>>(bsums);
    scan3_kernel<<<SCAN_NBLK, 1024, 0, stream>>>(off, bsums, counts);
    fill_kernel<<<NROWS / 256, 256, 0, stream>>>(ids, counts, rowidx);
    fuse_kernel<<<NROWS / 32, 512, 0, stream>>>(emb, WeP, ids, hB, GsB, actB, out);
    finalize_kernel<<<(NENT + 3) / 4, 256, 0, stream>>>(fast, slow, out, off, rowidx, nf, ns);
}

// Round 12
// 986.281 us; speedup vs baseline: 1.4832x; 1.0002x over previous
//
#include <hip/hip_runtime.h>
#include <hip/hip_bf16.h>
#include <cstdint>

#define NROWS 262144
#define HDIM  512
#define NENT  100000
#define SCAN_NBLK ((NENT + 1023) / 1024)

typedef __attribute__((ext_vector_type(4))) float  f32x4;
typedef __attribute__((ext_vector_type(8))) short  bf16x8;
typedef __attribute__((ext_vector_type(4))) short  bf16x4;

static __device__ __forceinline__ unsigned short f2bf(float x) {
    unsigned u = __float_as_uint(x);
    u += 0x7FFF + ((u >> 16) & 1);          // round-to-nearest-even
    return (unsigned short)(u >> 16);
}
static __device__ __forceinline__ float bf2f(unsigned short h) {
    return __uint_as_float(((unsigned)h) << 16);
}

// Pack W ([512][1024], y = x@W.T) into TWO per-wave-linear bf16 A-frag arrays:
//   WeP = W[:, 0:512]   (emb half),  WsP = W[:, 512:1024] (state half)
// index gg = ((w*16 + kt)*4 + ct)*64 + lane ; nt = w*4+ct ;
// lane l of frag (nt,kt) holds A[m=nt*16+(l&15)][k=kt*32+(l>>4)*8+j].
__global__ void pack_w_kernel(const float* __restrict__ W,
                              unsigned short* __restrict__ WeP,
                              unsigned short* __restrict__ WsP) {
    int g    = blockIdx.x * 256 + threadIdx.x;   // 65536
    int sel  = g >> 15;
    int gg   = g & 32767;
    int lane = gg & 63;
    int ct   = (gg >> 6) & 3;
    int kt   = (gg >> 8) & 15;
    int w    = gg >> 12;
    int col  = (w * 4 + ct) * 16 + (lane & 15);
    int k    = kt * 32 + ((lane >> 4) << 3) + sel * 512;
    const float* src = W + (size_t)col * 1024 + k;
    f32x4 v0 = *(const f32x4*)(src);
    f32x4 v1 = *(const f32x4*)(src + 4);
    bf16x8 ov;
#pragma unroll
    for (int i = 0; i < 4; ++i) {
        ov[i]     = (short)f2bf(v0[i]);
        ov[4 + i] = (short)f2bf(v1[i]);
    }
    unsigned short* dst = sel ? WsP : WeP;
    *(bf16x8*)(dst + (size_t)gg * 8) = ov;
}

// ---- counts zeroing as a plain kernel (NO hipMemsetAsync in the graph) ----
__global__ __launch_bounds__(256) void zero_kernel(unsigned* __restrict__ p) {
    int i = blockIdx.x * 256 + threadIdx.x;
    if (i < NENT) p[i] = 0u;
}

// ---- CSR build: counts -> 2-level exclusive scan -> fill row indices ----
__global__ __launch_bounds__(256) void count_kernel(const int* __restrict__ ids,
                                                    unsigned* __restrict__ counts) {
    int r = blockIdx.x * 256 + threadIdx.x;
    if (r < NROWS) atomicAdd(&counts[ids[r]], 1u);
}

__global__ __launch_bounds__(1024) void scan1_kernel(const unsigned* __restrict__ counts,
                                                     unsigned* __restrict__ off,
                                                     unsigned* __restrict__ bsums) {
    __shared__ unsigned tmp[1024];
    int i = blockIdx.x * 1024 + threadIdx.x;
    unsigned v = (i < NENT) ? counts[i] : 0u;
    tmp[threadIdx.x] = v;
    __syncthreads();
#pragma unroll
    for (int o = 1; o < 1024; o <<= 1) {
        unsigned a = (threadIdx.x >= o) ? tmp[threadIdx.x - o] : 0u;
        __syncthreads();
        tmp[threadIdx.x] += a;
        __syncthreads();
    }
    if (i < NENT) off[i] = tmp[threadIdx.x] - v;     // block-local exclusive
    if (threadIdx.x == 1023) bsums[blockIdx.x] = tmp[1023];
}

__global__ void scan2_kernel(unsigned* __restrict__ bsums) {
    if (threadIdx.x == 0 && blockIdx.x == 0) {
        unsigned s = 0;
        for (int i = 0; i < SCAN_NBLK; ++i) { unsigned t = bsums[i]; bsums[i] = s; s += t; }
    }
}

__global__ __launch_bounds__(1024) void scan3_kernel(unsigned* __restrict__ off,
                                                     const unsigned* __restrict__ bsums,
                                                     unsigned* __restrict__ cursor) {
    int i = blockIdx.x * 1024 + threadIdx.x;
    if (i < NENT) {
        unsigned o = off[i] + bsums[blockIdx.x];
        off[i] = o;
        cursor[i] = o;
    }
    if (i == 0) off[NENT] = NROWS;
}

__global__ __launch_bounds__(256) void fill_kernel(const int* __restrict__ ids,
                                                   unsigned* __restrict__ cursor,
                                                   int* __restrict__ rowidx) {
    int r = blockIdx.x * 256 + threadIdx.x;
    if (r < NROWS) {
        unsigned p = atomicAdd(&cursor[ids[r]], 1u);
        rowidx[p] = r;
    }
}

// Kernel A: per-entity precompute. 32 entities/block, 512 thr = 8 waves.
// h = LN(slow[e]) (coalesced, no gather); Gs = h @ Ws.T + b (K=512 GEMM,
// barrier-free loop, whole-K x in 32 KB LDS, Ws frags from L2 depth-2).
// Stores h, Gs as bf16; act flag as float. 100000 = 3125*32 exactly.
__global__ __launch_bounds__(512, 4) void entity_kernel(
    const float* __restrict__ slow, const unsigned short* __restrict__ WsP,
    const float* __restrict__ bias, unsigned short* __restrict__ hB,
    unsigned short* __restrict__ GsB, float* __restrict__ actB)
{
    __shared__ unsigned short xLds[2048 * 8];   // 32 KB: 32 tiles x 64 lanes x 16B
    __shared__ float muS[32], rsS[32], bS[512];

    const int t    = threadIdx.x;
    const int w    = t >> 6;          // 0..7
    const int lane = t & 63;
    const int brow = blockIdx.x * 32;

    if (t < 128) ((f32x4*)bS)[t] = ((const f32x4*)bias)[t];

    // ---- LN stats + is_active: 8 waves x 4 rows ----
    for (int rr = 0; rr < 4; ++rr) {
        int row = w * 4 + rr;
        int e   = brow + row;
        const float* sp = slow + (size_t)e * HDIM;
        f32x4 v0 = ((const f32x4*)sp)[lane * 2];
        f32x4 v1 = ((const f32x4*)sp)[lane * 2 + 1];
        float s = 0.f, s2 = 0.f, sa = 0.f;
#pragma unroll
        for (int i = 0; i < 4; ++i) {
            s  += v0[i] + v1[i];
            s2 += v0[i] * v0[i] + v1[i] * v1[i];
            sa += fabsf(v0[i]) + fabsf(v1[i]);
        }
#pragma unroll
        for (int m = 32; m >= 1; m >>= 1) {
            s  += __shfl_xor(s, m);
            s2 += __shfl_xor(s2, m);
            sa += __shfl_xor(sa, m);
        }
        if (lane == 0) {
            float mu  = s * (1.f / HDIM);
            float var = s2 * (1.f / HDIM) - mu * mu;
            muS[row] = mu;
            rsS[row] = rsqrtf(var + 1e-5f);
            actB[e]  = (sa > 1e-6f) ? 1.f : 0.f;
        }
    }
    __syncthreads();

    // ---- stage whole K=512 as LN(slow) bf16 fragments (4 slots/thread) ----
#pragma unroll
    for (int i = 0; i < 4; ++i) {
        int s  = t + i * 512;
        int T  = s >> 6, ls = s & 63;
        int row = (T & 1) * 16 + (ls & 15);
        int k   = (T >> 1) * 32 + ((ls >> 4) << 3);
        const float* p = slow + (size_t)(brow + row) * HDIM + k;
        f32x4 x0 = *(const f32x4*)p, x1 = *(const f32x4*)(p + 4);
        float mu = muS[row], rs = rsS[row];
        bf16x8 av;
#pragma unroll
        for (int j = 0; j < 4; ++j) {
            av[j]     = (short)f2bf((x0[j] - mu) * rs);
            av[4 + j] = (short)f2bf((x1[j] - mu) * rs);
        }
        ((bf16x8*)xLds)[s] = av;
    }
    __syncthreads();

    // ---- barrier-free K loop: wave w -> cols w*64..+63, depth-2 prefetch ----
    f32x4 zero4 = {0.f, 0.f, 0.f, 0.f};
    f32x4 acc[2][4];
#pragma unroll
    for (int i = 0; i < 2; ++i)
#pragma unroll
        for (int j = 0; j < 4; ++j) acc[i][j] = zero4;

    const unsigned short* wpW = WsP + (size_t)w * 32768 + (size_t)lane * 8;

#define LOADW(dst, kt)                                                  \
    {   _Pragma("unroll")                                               \
        for (int ct = 0; ct < 4; ++ct)                                  \
            dst[ct] = *(const bf16x8*)(wpW + ((kt) * 4 + ct) * 512);    \
    }
#define LOADX(dst, kt)                                                  \
    {   _Pragma("unroll")                                               \
        for (int rt = 0; rt < 2; ++rt)                                  \
            dst[rt] = ((const bf16x8*)xLds)[((kt) * 2 + rt) * 64 + lane]; \
    }
#define STEP(wf, xf)                                                    \
    {   _Pragma("unroll")                                               \
        for (int ct = 0; ct < 4; ++ct) {                                \
            acc[0][ct] = __builtin_amdgcn_mfma_f32_16x16x32_bf16(wf[ct], xf[0], acc[0][ct], 0, 0, 0); \
            acc[1][ct] = __builtin_amdgcn_mfma_f32_16x16x32_bf16(wf[ct], xf[1], acc[1][ct], 0, 0, 0); \
        }                                                               \
    }

    {
        bf16x8 wA[4], wB[4], xA[2], xB[2];
        LOADW(wA, 0); LOADX(xA, 0);
#pragma unroll
        for (int kt = 0; kt < 16; kt += 2) {
            if (kt + 1 < 16) { LOADW(wB, kt + 1); LOADX(xB, kt + 1); }
            STEP(wA, xA);
            if (kt + 2 < 16) { LOADW(wA, kt + 2); LOADX(xA, kt + 2); }
            if (kt + 1 < 16) STEP(wB, xB);
        }
    }

    // ---- epilogue: Gs = acc + b -> bf16; h from LDS -> bf16 ----
#pragma unroll
    for (int rt = 0; rt < 2; ++rt) {
        int e = brow + rt * 16 + (lane & 15);
#pragma unroll
        for (int ct = 0; ct < 4; ++ct) {
            int col0 = w * 64 + ct * 16 + ((lane >> 4) << 2);
            f32x4 bv = *(const f32x4*)&bS[col0];
            bf16x4 gv;
#pragma unroll
            for (int r = 0; r < 4; ++r) gv[r] = (short)f2bf(acc[rt][ct][r] + bv[r]);
            *(bf16x4*)(GsB + (size_t)e * HDIM + col0) = gv;
        }
    }
#pragma unroll
    for (int i = 0; i < 4; ++i) {
        int s  = t + i * 512;
        int T  = s >> 6, ls = s & 63;
        int row = (T & 1) * 16 + (ls & 15);
        int k   = (T >> 1) * 32 + ((ls >> 4) << 3);
        *(bf16x8*)(hB + (size_t)(brow + row) * HDIM + k) = ((const bf16x8*)xLds)[s];
    }
}

// Kernel B: row GEMM. 32 rows/block, 512 thr = 8 waves; z-logits =
// emb @ We.T (K=512, streaming, no gather/LN) ; epilogue gathers Gs[id]
// (includes bias), h[id], act[id] (bf16/f32, L3-resident) and blends.
__global__ __launch_bounds__(512, 4) void fuse_kernel(
    const float* __restrict__ emb, const unsigned short* __restrict__ WeP,
    const int* __restrict__ ids, const unsigned short* __restrict__ hB,
    const unsigned short* __restrict__ GsB, const float* __restrict__ actB,
    float* __restrict__ out)
{
    __shared__ unsigned short xLds[2048 * 8];   // 32 KB
    __shared__ int idS[32];

    const int t    = threadIdx.x;
    const int w    = t >> 6;
    const int lane = t & 63;
    const int brow = blockIdx.x * 32;

    if (t < 32) idS[t] = ids[brow + t];

    // ---- stage whole K=512 emb as bf16 fragments (4 slots/thread) ----
#pragma unroll
    for (int i = 0; i < 4; ++i) {
        int s  = t + i * 512;
        int T  = s >> 6, ls = s & 63;
        int row = (T & 1) * 16 + (ls & 15);
        int k   = (T >> 1) * 32 + ((ls >> 4) << 3);
        const float* p = emb + (size_t)(brow + row) * HDIM + k;
        f32x4 x0 = *(const f32x4*)p, x1 = *(const f32x4*)(p + 4);
        bf16x8 av;
#pragma unroll
        for (int j = 0; j < 4; ++j) {
            av[j]     = (short)f2bf(x0[j]);
            av[4 + j] = (short)f2bf(x1[j]);
        }
        ((bf16x8*)xLds)[s] = av;
    }
    __syncthreads();

    f32x4 zero4 = {0.f, 0.f, 0.f, 0.f};
    f32x4 acc[2][4];
#pragma unroll
    for (int i = 0; i < 2; ++i)
#pragma unroll
        for (int j = 0; j < 4; ++j) acc[i][j] = zero4;

    const unsigned short* wpW = WeP + (size_t)w * 32768 + (size_t)lane * 8;

    {
        bf16x8 wA[4], wB[4], xA[2], xB[2];
        LOADW(wA, 0); LOADX(xA, 0);
#pragma unroll
        for (int kt = 0; kt < 16; kt += 2) {
            if (kt + 1 < 16) { LOADW(wB, kt + 1); LOADX(xB, kt + 1); }
            STEP(wA, xA);
            if (kt + 2 < 16) { LOADW(wA, kt + 2); LOADX(xA, kt + 2); }
            if (kt + 1 < 16) STEP(wB, xB);
        }
    }
#undef LOADW
#undef LOADX
#undef STEP

    // ---- epilogue: z = sigmoid(acc + Gs[id]); out = act ? z*e+(1-z)*h : e ----
#pragma unroll
    for (int rt = 0; rt < 2; ++rt) {
        int rowl = rt * 16 + (lane & 15);
        int grow = brow + rowl;
        int id   = idS[rowl];
        float act = actB[id];
        const unsigned short* gsP = GsB + (size_t)id * HDIM;
        const unsigned short* hP  = hB  + (size_t)id * HDIM;
        float* outP = out + (size_t)grow * HDIM;
#pragma unroll
        for (int ct = 0; ct < 4; ++ct) {
            int col0 = w * 64 + ct * 16 + ((lane >> 4) << 2);
            // emb[row][col0..3] from LDS frag layout
            int Te = ((col0 >> 5) * 2 + rt) * 64 + (((col0 >> 3) & 3) << 4) + (lane & 15);
            const unsigned short* pe = xLds + Te * 8 + (col0 & 7);
            bf16x4 gv = *(const bf16x4*)(gsP + col0);
            bf16x4 hv = *(const bf16x4*)(hP + col0);
            f32x4 o;
#pragma unroll
            for (int r = 0; r < 4; ++r) {
                float ev = bf2f(pe[r]);
                float logit = acc[rt][ct][r] + bf2f(gv[r]);
                float z = 1.f / (1.f + __expf(-logit));
                float fused = z * ev + (1.f - z) * bf2f(hv[r]);
                o[r] = (act > 0.f) ? fused : ev;
            }
            *(f32x4*)(outP + col0) = o;
        }
    }
}

// Per-entity: gather its rows from `out` (CSR), mean -> EMA fast, norm-gated slow.
__global__ __launch_bounds__(256) void finalize_kernel(
    const float* __restrict__ fast, const float* __restrict__ slow,
    const float* __restrict__ out, const unsigned* __restrict__ off,
    const int* __restrict__ rowidx, float* __restrict__ nf, float* __restrict__ ns)
{
    int e = blockIdx.x * 4 + (threadIdx.x >> 6);
    if (e >= NENT) return;
    int lane = threadIdx.x & 63;
    size_t base = (size_t)e * HDIM + lane * 8;

    f32x4 f0 = *(const f32x4*)(fast + base), f1 = *(const f32x4*)(fast + base + 4);
    f32x4 l0 = *(const f32x4*)(slow + base), l1 = *(const f32x4*)(slow + base + 4);

    unsigned o0 = off[e], o1 = off[e + 1];
    int c = (int)(o1 - o0);

    if (c == 0) {
        *(f32x4*)(nf + base)     = f0;
        *(f32x4*)(nf + base + 4) = f1;
        *(f32x4*)(ns + base)     = l0;
        *(f32x4*)(ns + base + 4) = l1;
        return;
    }

    f32x4 s0 = {0.f, 0.f, 0.f, 0.f}, s1 = {0.f, 0.f, 0.f, 0.f};
    for (int j = 0; j < c; ++j) {
        int r = rowidx[o0 + j];
        const float* p = out + (size_t)r * HDIM + lane * 8;
        s0 += *(const f32x4*)p;
        s1 += *(const f32x4*)(p + 4);
    }

    float inv = 0.5f / (float)c;          // ALPHA / count
    f32x4 n0, n1, d0, d1;
    float ss = 0.f;
#pragma unroll
    for (int i = 0; i < 4; ++i) {
        n0[i] = 0.5f * f0[i] + s0[i] * inv;
        n1[i] = 0.5f * f1[i] + s1[i] * inv;
        d0[i] = n0[i] - l0[i]; ss += d0[i] * d0[i];
        d1[i] = n1[i] - l1[i]; ss += d1[i] * d1[i];
    }
#pragma unroll
    for (int m = 32; m >= 1; m >>= 1) ss += __shfl_xor(ss, m);
    float delta = sqrtf(ss);
    float gate  = 1.f / (1.f + expf(-5.f * (delta - 0.5f)));

    f32x4 o0v, o1v;
#pragma unroll
    for (int i = 0; i < 4; ++i) {
        o0v[i] = l0[i] + gate * d0[i];
        o1v[i] = l1[i] + gate * d1[i];
    }
    *(f32x4*)(nf + base)     = n0;
    *(f32x4*)(nf + base + 4) = n1;
    *(f32x4*)(ns + base)     = o0v;
    *(f32x4*)(ns + base + 4) = o1v;
}

extern "C" void kernel_launch(void* const* d_in, const int* in_sizes, int n_in,
                              void* d_out, int out_size, void* d_ws, size_t ws_size,
                              hipStream_t stream) {
    const float* emb  = (const float*)d_in[0];
    const float* slow = (const float*)d_in[1];
    const float* fast = (const float*)d_in[2];
    const float* W    = (const float*)d_in[3];
    const float* bias = (const float*)d_in[4];
    const int*   ids  = (const int*)d_in[5];

    float* out = (float*)d_out;
    float* nf  = out + (size_t)NROWS * HDIM;
    float* ns  = nf + (size_t)NENT * HDIM;

    // h/Gs (bf16, 102 MB each) live in the nf/ns regions until finalize
    // overwrites them (A writes -> B reads -> finalize writes).
    unsigned short* hB  = (unsigned short*)nf;
    unsigned short* GsB = (unsigned short*)ns;

    // ws: WeP 512K | WsP 512K | actB 400K | counts 400K | off 400K+4 | bsums | rowidx 1M
    unsigned short* WeP = (unsigned short*)d_ws;
    unsigned short* WsP = (unsigned short*)((char*)d_ws + (512u << 10));
    float* actB         = (float*)((char*)d_ws + (1024u << 10));
    unsigned* counts    = (unsigned*)((char*)d_ws + (1536u << 10));   // reused as cursor
    unsigned* off       = (unsigned*)((char*)d_ws + (2048u << 10));
    unsigned* bsums     = (unsigned*)((char*)d_ws + (2560u << 10));
    int*      rowidx    = (int*)((char*)d_ws + (2560u << 10) + 4096);

    zero_kernel<<<(NENT + 255) / 256, 256, 0, stream>>>(counts);
    pack_w_kernel<<<256, 256, 0, stream>>>(W, WeP, WsP);
    entity_kernel<<<NENT / 32, 512, 0, stream>>>(slow, WsP, bias, hB, GsB, actB);
    count_kernel<<<NROWS / 256, 256, 0, stream>>>(ids, counts);
    scan1_kernel<<<SCAN_NBLK, 1024, 0, stream>>>(counts, off, bsums);
    scan2_kernel<<<1, 64, 0, stream>>>(bsums);
    scan3_kernel<<<SCAN_NBLK, 1024, 0, stream>>>(off, bsums, counts);
    fill_kernel<<<NROWS / 256, 256, 0, stream>>>(ids, counts, rowidx);
    fuse_kernel<<<NROWS / 32, 512, 0, stream>>>(emb, WeP, ids, hB, GsB, actB, out);
    finalize_kernel<<<(NENT + 3) / 4, 256, 0, stream>>>(fast, slow, out, off, rowidx, nf, ns);
}

// Round 13
// 974.576 us; speedup vs baseline: 1.5010x; 1.0120x over previous
//
#include <hip/hip_runtime.h>
#include <hip/hip_bf16.h>
#include <cstdint>

#define NROWS 262144
#define HDIM  512
#define NENT  100000
#define SCAN_NBLK ((NENT + 1023) / 1024)

typedef __attribute__((ext_vector_type(4))) float  f32x4;
typedef __attribute__((ext_vector_type(8))) short  bf16x8;
typedef __attribute__((ext_vector_type(4))) short  bf16x4;

static __device__ __forceinline__ unsigned short f2bf(float x) {
    unsigned u = __float_as_uint(x);
    u += 0x7FFF + ((u >> 16) & 1);          // round-to-nearest-even
    return (unsigned short)(u >> 16);
}
static __device__ __forceinline__ float bf2f(unsigned short h) {
    return __uint_as_float(((unsigned)h) << 16);
}

// Pack W ([512][1024], y = x@W.T) into TWO bf16 A-frag arrays in (nt,kt)
// order: dst[(nt*16 + kt)*64 + lane], nt 0..31, kt 0..15.
//   WeP = W[:, 0:512] (emb half), WsP = W[:, 512:1024] (state half).
// Lane l of frag (nt,kt) holds A[m=nt*16+(l&15)][k=kt*32+(l>>4)*8+j].
__global__ void pack_w_kernel(const float* __restrict__ W,
                              unsigned short* __restrict__ WeP,
                              unsigned short* __restrict__ WsP) {
    int g    = blockIdx.x * 256 + threadIdx.x;   // 65536
    int sel  = g >> 15;
    int gg   = g & 32767;
    int lane = gg & 63;
    int kt   = (gg >> 6) & 15;
    int nt   = gg >> 10;
    int col  = nt * 16 + (lane & 15);
    int k    = kt * 32 + ((lane >> 4) << 3) + sel * 512;
    const float* src = W + (size_t)col * 1024 + k;
    f32x4 v0 = *(const f32x4*)(src);
    f32x4 v1 = *(const f32x4*)(src + 4);
    bf16x8 ov;
#pragma unroll
    for (int i = 0; i < 4; ++i) {
        ov[i]     = (short)f2bf(v0[i]);
        ov[4 + i] = (short)f2bf(v1[i]);
    }
    unsigned short* dst = sel ? WsP : WeP;
    *(bf16x8*)(dst + (size_t)gg * 8) = ov;
}

// ---- counts zeroing as a plain kernel ----
__global__ __launch_bounds__(256) void zero_kernel(unsigned* __restrict__ p) {
    int i = blockIdx.x * 256 + threadIdx.x;
    if (i < NENT) p[i] = 0u;
}

// ---- CSR build: counts -> 2-level exclusive scan -> fill row indices ----
__global__ __launch_bounds__(256) void count_kernel(const int* __restrict__ ids,
                                                    unsigned* __restrict__ counts) {
    int r = blockIdx.x * 256 + threadIdx.x;
    if (r < NROWS) atomicAdd(&counts[ids[r]], 1u);
}

__global__ __launch_bounds__(1024) void scan1_kernel(const unsigned* __restrict__ counts,
                                                     unsigned* __restrict__ off,
                                                     unsigned* __restrict__ bsums) {
    __shared__ unsigned tmp[1024];
    int i = blockIdx.x * 1024 + threadIdx.x;
    unsigned v = (i < NENT) ? counts[i] : 0u;
    tmp[threadIdx.x] = v;
    __syncthreads();
#pragma unroll
    for (int o = 1; o < 1024; o <<= 1) {
        unsigned a = (threadIdx.x >= o) ? tmp[threadIdx.x - o] : 0u;
        __syncthreads();
        tmp[threadIdx.x] += a;
        __syncthreads();
    }
    if (i < NENT) off[i] = tmp[threadIdx.x] - v;     // block-local exclusive
    if (threadIdx.x == 1023) bsums[blockIdx.x] = tmp[1023];
}

__global__ void scan2_kernel(unsigned* __restrict__ bsums) {
    if (threadIdx.x == 0 && blockIdx.x == 0) {
        unsigned s = 0;
        for (int i = 0; i < SCAN_NBLK; ++i) { unsigned t = bsums[i]; bsums[i] = s; s += t; }
    }
}

__global__ __launch_bounds__(1024) void scan3_kernel(unsigned* __restrict__ off,
                                                     const unsigned* __restrict__ bsums,
                                                     unsigned* __restrict__ cursor) {
    int i = blockIdx.x * 1024 + threadIdx.x;
    if (i < NENT) {
        unsigned o = off[i] + bsums[blockIdx.x];
        off[i] = o;
        cursor[i] = o;
    }
    if (i == 0) off[NENT] = NROWS;
}

__global__ __launch_bounds__(256) void fill_kernel(const int* __restrict__ ids,
                                                   unsigned* __restrict__ cursor,
                                                   int* __restrict__ rowidx) {
    int r = blockIdx.x * 256 + threadIdx.x;
    if (r < NROWS) {
        unsigned p = atomicAdd(&cursor[ids[r]], 1u);
        rowidx[p] = r;
    }
}

// Kernel A: per-entity precompute. 32 entities/block, 512 thr = 8 waves.
// h = LN(slow[e]); Gs = h @ Ws.T + b (K=512, whole-K LDS, barrier-free,
// depth-2 W prefetch from L2). Stores h, Gs bf16; act flag f32.
__global__ __launch_bounds__(512, 4) void entity_kernel(
    const float* __restrict__ slow, const unsigned short* __restrict__ WsP,
    const float* __restrict__ bias, unsigned short* __restrict__ hB,
    unsigned short* __restrict__ GsB, float* __restrict__ actB)
{
    __shared__ unsigned short xLds[2048 * 8];   // 32 KB
    __shared__ float muS[32], rsS[32], bS[512];

    const int t    = threadIdx.x;
    const int w    = t >> 6;          // 0..7
    const int lane = t & 63;
    const int brow = blockIdx.x * 32;

    if (t < 128) ((f32x4*)bS)[t] = ((const f32x4*)bias)[t];

    for (int rr = 0; rr < 4; ++rr) {
        int row = w * 4 + rr;
        int e   = brow + row;
        const float* sp = slow + (size_t)e * HDIM;
        f32x4 v0 = ((const f32x4*)sp)[lane * 2];
        f32x4 v1 = ((const f32x4*)sp)[lane * 2 + 1];
        float s = 0.f, s2 = 0.f, sa = 0.f;
#pragma unroll
        for (int i = 0; i < 4; ++i) {
            s  += v0[i] + v1[i];
            s2 += v0[i] * v0[i] + v1[i] * v1[i];
            sa += fabsf(v0[i]) + fabsf(v1[i]);
        }
#pragma unroll
        for (int m = 32; m >= 1; m >>= 1) {
            s  += __shfl_xor(s, m);
            s2 += __shfl_xor(s2, m);
            sa += __shfl_xor(sa, m);
        }
        if (lane == 0) {
            float mu  = s * (1.f / HDIM);
            float var = s2 * (1.f / HDIM) - mu * mu;
            muS[row] = mu;
            rsS[row] = rsqrtf(var + 1e-5f);
            actB[e]  = (sa > 1e-6f) ? 1.f : 0.f;
        }
    }
    __syncthreads();

    // stage whole K=512 as LN(slow) bf16 fragments: tile T = kt*2 + rt
#pragma unroll
    for (int i = 0; i < 4; ++i) {
        int s  = t + i * 512;
        int T  = s >> 6, ls = s & 63;
        int row = (T & 1) * 16 + (ls & 15);
        int k   = (T >> 1) * 32 + ((ls >> 4) << 3);
        const float* p = slow + (size_t)(brow + row) * HDIM + k;
        f32x4 x0 = *(const f32x4*)p, x1 = *(const f32x4*)(p + 4);
        float mu = muS[row], rs = rsS[row];
        bf16x8 av;
#pragma unroll
        for (int j = 0; j < 4; ++j) {
            av[j]     = (short)f2bf((x0[j] - mu) * rs);
            av[4 + j] = (short)f2bf((x1[j] - mu) * rs);
        }
        ((bf16x8*)xLds)[s] = av;
    }
    __syncthreads();

    f32x4 zero4 = {0.f, 0.f, 0.f, 0.f};
    f32x4 acc[2][4];
#pragma unroll
    for (int i = 0; i < 2; ++i)
#pragma unroll
        for (int j = 0; j < 4; ++j) acc[i][j] = zero4;

#define LOADW_A(dst, kt)                                                \
    {   _Pragma("unroll")                                               \
        for (int ct = 0; ct < 4; ++ct)                                  \
            dst[ct] = *(const bf16x8*)(WsP +                            \
                ((size_t)(((w * 4 + ct) * 16 + (kt)) * 64 + lane) << 3)); \
    }
#define LOADX_A(dst, kt)                                                \
    {   _Pragma("unroll")                                               \
        for (int rt = 0; rt < 2; ++rt)                                  \
            dst[rt] = ((const bf16x8*)xLds)[((kt) * 2 + rt) * 64 + lane]; \
    }
#define STEP(wf, xf)                                                    \
    {   _Pragma("unroll")                                               \
        for (int ct = 0; ct < 4; ++ct) {                                \
            acc[0][ct] = __builtin_amdgcn_mfma_f32_16x16x32_bf16(wf[ct], xf[0], acc[0][ct], 0, 0, 0); \
            acc[1][ct] = __builtin_amdgcn_mfma_f32_16x16x32_bf16(wf[ct], xf[1], acc[1][ct], 0, 0, 0); \
        }                                                               \
    }

    {
        bf16x8 wA[4], wB[4], xA[2], xB[2];
        LOADW_A(wA, 0); LOADX_A(xA, 0);
#pragma unroll
        for (int kt = 0; kt < 16; kt += 2) {
            if (kt + 1 < 16) { LOADW_A(wB, kt + 1); LOADX_A(xB, kt + 1); }
            STEP(wA, xA);
            if (kt + 2 < 16) { LOADW_A(wA, kt + 2); LOADX_A(xA, kt + 2); }
            if (kt + 1 < 16) STEP(wB, xB);
        }
    }
#undef LOADW_A
#undef LOADX_A

    // epilogue: Gs = acc + b -> bf16; h from LDS -> bf16
#pragma unroll
    for (int rt = 0; rt < 2; ++rt) {
        int e = brow + rt * 16 + (lane & 15);
#pragma unroll
        for (int ct = 0; ct < 4; ++ct) {
            int col0 = w * 64 + ct * 16 + ((lane >> 4) << 2);
            f32x4 bv = *(const f32x4*)&bS[col0];
            bf16x4 gv;
#pragma unroll
            for (int r = 0; r < 4; ++r) gv[r] = (short)f2bf(acc[rt][ct][r] + bv[r]);
            *(bf16x4*)(GsB + (size_t)e * HDIM + col0) = gv;
        }
    }
#pragma unroll
    for (int i = 0; i < 4; ++i) {
        int s  = t + i * 512;
        int T  = s >> 6, ls = s & 63;
        int row = (T & 1) * 16 + (ls & 15);
        int k   = (T >> 1) * 32 + ((ls >> 4) << 3);
        *(bf16x8*)(hB + (size_t)(brow + row) * HDIM + k) = ((const bf16x8*)xLds)[s];
    }
}

// Kernel B v3: 64 rows/block, 1024 thr = 16 waves (2M x 8N; wave = 32r x 64c,
// acc 2x4 like v2). Whole-K=512 emb staged bf16 in 64 KB LDS once, then
// barrier-free K loop: W frags from L2 depth-2; W L2 traffic halves vs v2
// (4096 blocks x 512 KB). Epilogue: emb from LDS; gather Gs/h/act by id.
__global__ __launch_bounds__(1024, 4) void fuse_kernel(
    const float* __restrict__ emb, const unsigned short* __restrict__ WeP,
    const int* __restrict__ ids, const unsigned short* __restrict__ hB,
    const unsigned short* __restrict__ GsB, const float* __restrict__ actB,
    float* __restrict__ out)
{
    __shared__ unsigned short xLds[4096 * 8];   // 64 KB: tile T = kt*4 + rt
    __shared__ int idS[64];

    const int t    = threadIdx.x;
    const int w    = t >> 6;          // 0..15
    const int lane = t & 63;
    const int wm   = w >> 3;          // 0..1  row half
    const int wn   = w & 7;           // 0..7  col group
    const int brow = blockIdx.x * 64;

    if (t < 64) idS[t] = ids[brow + t];

    // stage whole K=512 for 64 rows: 4096 slots / 1024 thr = 4 each
#pragma unroll
    for (int i = 0; i < 4; ++i) {
        int s  = t + i * 1024;
        int T  = s >> 6, ls = s & 63;
        int kt  = T >> 2, rt = T & 3;
        int row = rt * 16 + (ls & 15);
        int k   = kt * 32 + ((ls >> 4) << 3);
        const float* p = emb + (size_t)(brow + row) * HDIM + k;
        f32x4 x0 = *(const f32x4*)p, x1 = *(const f32x4*)(p + 4);
        bf16x8 av;
#pragma unroll
        for (int j = 0; j < 4; ++j) {
            av[j]     = (short)f2bf(x0[j]);
            av[4 + j] = (short)f2bf(x1[j]);
        }
        ((bf16x8*)xLds)[s] = av;
    }
    __syncthreads();

    f32x4 zero4 = {0.f, 0.f, 0.f, 0.f};
    f32x4 acc[2][4];
#pragma unroll
    for (int i = 0; i < 2; ++i)
#pragma unroll
        for (int j = 0; j < 4; ++j) acc[i][j] = zero4;

#define LOADW_B(dst, kt)                                                \
    {   _Pragma("unroll")                                               \
        for (int ct = 0; ct < 4; ++ct)                                  \
            dst[ct] = *(const bf16x8*)(WeP +                            \
                ((size_t)(((wn * 4 + ct) * 16 + (kt)) * 64 + lane) << 3)); \
    }
#define LOADX_B(dst, kt)                                                \
    {   _Pragma("unroll")                                               \
        for (int rt = 0; rt < 2; ++rt)                                  \
            dst[rt] = ((const bf16x8*)xLds)[((kt) * 4 + wm * 2 + rt) * 64 + lane]; \
    }

    {
        bf16x8 wA[4], wB[4], xA[2], xB[2];
        LOADW_B(wA, 0); LOADX_B(xA, 0);
#pragma unroll
        for (int kt = 0; kt < 16; kt += 2) {
            if (kt + 1 < 16) { LOADW_B(wB, kt + 1); LOADX_B(xB, kt + 1); }
            STEP(wA, xA);
            if (kt + 2 < 16) { LOADW_B(wA, kt + 2); LOADX_B(xA, kt + 2); }
            if (kt + 1 < 16) STEP(wB, xB);
        }
    }
#undef LOADW_B
#undef LOADX_B
#undef STEP

    // epilogue: z = sigmoid(acc + Gs[id]); out = act ? z*e+(1-z)*h : e
#pragma unroll
    for (int rt = 0; rt < 2; ++rt) {
        int rowl = wm * 32 + rt * 16 + (lane & 15);
        int grow = brow + rowl;
        int id   = idS[rowl];
        float act = actB[id];
        const unsigned short* gsP = GsB + (size_t)id * HDIM;
        const unsigned short* hP  = hB  + (size_t)id * HDIM;
        float* outP = out + (size_t)grow * HDIM;
#pragma unroll
        for (int ct = 0; ct < 4; ++ct) {
            int col0 = wn * 64 + ct * 16 + ((lane >> 4) << 2);
            // emb[rowl][col0..3] from LDS: T = (col0>>5)*4 + (wm*2+rt)
            int Te = ((col0 >> 5) * 4 + wm * 2 + rt) * 64 + (((col0 >> 3) & 3) << 4) + (lane & 15);
            const unsigned short* pe = xLds + Te * 8 + (col0 & 7);
            bf16x4 gv = *(const bf16x4*)(gsP + col0);
            bf16x4 hv = *(const bf16x4*)(hP + col0);
            f32x4 o;
#pragma unroll
            for (int r = 0; r < 4; ++r) {
                float ev = bf2f(pe[r]);
                float logit = acc[rt][ct][r] + bf2f(gv[r]);
                float z = 1.f / (1.f + __expf(-logit));
                float fused = z * ev + (1.f - z) * bf2f(hv[r]);
                o[r] = (act > 0.f) ? fused : ev;
            }
            *(f32x4*)(outP + col0) = o;
        }
    }
}

// Per-entity: gather its rows from `out` (CSR), mean -> EMA fast, norm-gated slow.
__global__ __launch_bounds__(256) void finalize_kernel(
    const float* __restrict__ fast, const float* __restrict__ slow,
    const float* __restrict__ out, const unsigned* __restrict__ off,
    const int* __restrict__ rowidx, float* __restrict__ nf, float* __restrict__ ns)
{
    int e = blockIdx.x * 4 + (threadIdx.x >> 6);
    if (e >= NENT) return;
    int lane = threadIdx.x & 63;
    size_t base = (size_t)e * HDIM + lane * 8;

    f32x4 f0 = *(const f32x4*)(fast + base), f1 = *(const f32x4*)(fast + base + 4);
    f32x4 l0 = *(const f32x4*)(slow + base), l1 = *(const f32x4*)(slow + base + 4);

    unsigned o0 = off[e], o1 = off[e + 1];
    int c = (int)(o1 - o0);

    if (c == 0) {
        *(f32x4*)(nf + base)     = f0;
        *(f32x4*)(nf + base + 4) = f1;
        *(f32x4*)(ns + base)     = l0;
        *(f32x4*)(ns + base + 4) = l1;
        return;
    }

    f32x4 s0 = {0.f, 0.f, 0.f, 0.f}, s1 = {0.f, 0.f, 0.f, 0.f};
    for (int j = 0; j < c; ++j) {
        int r = rowidx[o0 + j];
        const float* p = out + (size_t)r * HDIM + lane * 8;
        s0 += *(const f32x4*)p;
        s1 += *(const f32x4*)(p + 4);
    }

    float inv = 0.5f / (float)c;          // ALPHA / count
    f32x4 n0, n1, d0, d1;
    float ss = 0.f;
#pragma unroll
    for (int i = 0; i < 4; ++i) {
        n0[i] = 0.5f * f0[i] + s0[i] * inv;
        n1[i] = 0.5f * f1[i] + s1[i] * inv;
        d0[i] = n0[i] - l0[i]; ss += d0[i] * d0[i];
        d1[i] = n1[i] - l1[i]; ss += d1[i] * d1[i];
    }
#pragma unroll
    for (int m = 32; m >= 1; m >>= 1) ss += __shfl_xor(ss, m);
    float delta = sqrtf(ss);
    float gate  = 1.f / (1.f + expf(-5.f * (delta - 0.5f)));

    f32x4 o0v, o1v;
#pragma unroll
    for (int i = 0; i < 4; ++i) {
        o0v[i] = l0[i] + gate * d0[i];
        o1v[i] = l1[i] + gate * d1[i];
    }
    *(f32x4*)(nf + base)     = n0;
    *(f32x4*)(nf + base + 4) = n1;
    *(f32x4*)(ns + base)     = o0v;
    *(f32x4*)(ns + base + 4) = o1v;
}

extern "C" void kernel_launch(void* const* d_in, const int* in_sizes, int n_in,
                              void* d_out, int out_size, void* d_ws, size_t ws_size,
                              hipStream_t stream) {
    const float* emb  = (const float*)d_in[0];
    const float* slow = (const float*)d_in[1];
    const float* fast = (const float*)d_in[2];
    const float* W    = (const float*)d_in[3];
    const float* bias = (const float*)d_in[4];
    const int*   ids  = (const int*)d_in[5];

    float* out = (float*)d_out;
    float* nf  = out + (size_t)NROWS * HDIM;
    float* ns  = nf + (size_t)NENT * HDIM;

    // h/Gs (bf16) live in the nf/ns regions until finalize overwrites them.
    unsigned short* hB  = (unsigned short*)nf;
    unsigned short* GsB = (unsigned short*)ns;

    // ws: WeP 512K | WsP 512K | actB 400K | counts 400K | off 400K+4 | bsums | rowidx 1M
    unsigned short* WeP = (unsigned short*)d_ws;
    unsigned short* WsP = (unsigned short*)((char*)d_ws + (512u << 10));
    float* actB         = (float*)((char*)d_ws + (1024u << 10));
    unsigned* counts    = (unsigned*)((char*)d_ws + (1536u << 10));   // reused as cursor
    unsigned* off       = (unsigned*)((char*)d_ws + (2048u << 10));
    unsigned* bsums     = (unsigned*)((char*)d_ws + (2560u << 10));
    int*      rowidx    = (int*)((char*)d_ws + (2560u << 10) + 4096);

    zero_kernel<<<(NENT + 255) / 256, 256, 0, stream>>>(counts);
    pack_w_kernel<<<256, 256, 0, stream>>>(W, WeP, WsP);
    entity_kernel<<<NENT / 32, 512, 0, stream>>>(slow, WsP, bias, hB, GsB, actB);
    count_kernel<<<NROWS / 256, 256, 0, stream>>>(ids, counts);
    scan1_kernel<<<SCAN_NBLK, 1024, 0, stream>>>(counts, off, bsums);
    scan2_kernel<<<1, 64, 0, stream>>>(bsums);
    scan3_kernel<<<SCAN_NBLK, 1024, 0, stream>>>(off, bsums, counts);
    fill_kernel<<<NROWS / 256, 256, 0, stream>>>(ids, counts, rowidx);
    fuse_kernel<<<NROWS / 64, 1024, 0, stream>>>(emb, WeP, ids, hB, GsB, actB, out);
    finalize_kernel<<<(NENT + 3) / 4, 256, 0, stream>>>(fast, slow, out, off, rowidx, nf, ns);
}